// Round 2
// baseline (574.604 us; speedup 1.0000x reference)
//
#include <hip/hip_runtime.h>

#define FC 32768
#define FF 131072
#define LRELU_SLOPE 0.2f
#define ACT_GAIN 1.4142135623730951f
#define CLAMP_V 256.0f

typedef __bf16 bf16x8 __attribute__((ext_vector_type(8)));
typedef float f32x4 __attribute__((ext_vector_type(4)));
typedef unsigned short u16x4 __attribute__((ext_vector_type(4)));

static __device__ __forceinline__ unsigned short f2bf(float f) {
    unsigned u = __float_as_uint(f);
    u += 0x7FFFu + ((u >> 16) & 1u);
    return (unsigned short)(u >> 16);
}
static __device__ __forceinline__ float bf2f(unsigned short u) {
    return __uint_as_float(((unsigned)u) << 16);
}
static __device__ __forceinline__ float actf(float v) {
    v = (v < 0.f) ? v * LRELU_SLOPE : v;
    v *= ACT_GAIN;
    return fminf(fmaxf(v, -CLAMP_V), CLAMP_V);
}

// ---------------- styles (affine, f32) + zero-row init ----------------
__global__ void k_prep(const float* __restrict__ wsvec,
                       const float* __restrict__ a0w, const float* __restrict__ a0b,
                       const float* __restrict__ a1w, const float* __restrict__ a1b,
                       const float* __restrict__ a2w, const float* __restrict__ a2b,
                       float* __restrict__ s0, float* __restrict__ s1, float* __restrict__ s2,
                       unsigned* __restrict__ zrow)
{
    int t = threadIdx.x;
    if (t >= 352) {
        int z = t - 352;
        if (z < 64) zrow[z] = 0u;  // 256B zero row for padded gathers
        return;
    }
    int level, o;
    const float *W, *bptr; float* out;
    if (t < 128)       { level = 0; o = t;       W = a0w; bptr = a0b; out = s0; }
    else if (t < 256)  { level = 1; o = t - 128; W = a1w; bptr = a1b; out = s1; }
    else               { level = 2; o = t - 256; W = a2w; bptr = a2b; out = s2; }
    const float* wrow = wsvec + level * 512;
    const float* Wr = W + o * 512;
    float acc = 0.f;
    for (int d = 0; d < 512; ++d) acc += wrow[d] * Wr[d];
    float v = acc * 0.04419417382415922f /* 1/sqrt(512) */ + bptr[o];
    if (level == 2) v *= 0.10206207261596577f;  // 1/sqrt(96) torgb weight gain
    out[o] = v;
}

// ---------------- concat(x, shape_feat) f32 -> bf16 [FC][128] ----------------
__global__ void k_cvt(const float* __restrict__ x, const float* __restrict__ sf,
                      u16x4* __restrict__ xcat)
{
    int gid = blockIdx.x * 256 + threadIdx.x;   // FC*32 threads, 4 channels each
    int f = gid >> 5;
    int c4 = (gid & 31) * 4;
    f32x4 v;
    if (c4 < 96) v = *(const f32x4*)(x + (size_t)f * 96 + c4);
    else         v = *(const f32x4*)(sf + (size_t)f * 32 + (c4 - 96));
    u16x4 o;
    o.x = f2bf(v.x); o.y = f2bf(v.y); o.z = f2bf(v.z); o.w = f2bf(v.w);
    xcat[gid] = o;
}

// ---------------- modulate + demodulate weights -> bf16 [3][O][128] ----------------
__global__ void k_modw(const float* __restrict__ wc, const float* __restrict__ wsd,
                       const float* __restrict__ wcr, const float* __restrict__ s,
                       unsigned short* __restrict__ out, int O)
{
    int o = blockIdx.x;
    int i = threadIdx.x;  // 128
    float sv = s[i];
    float pc = wc[o * 128 + i] * sv;
    float ps = wsd[o * 128 + i] * sv;
    float pr = wcr[o * 128 + i] * sv;
    float part = pc * pc + 4.f * ps * ps + 4.f * pr * pr;
    __shared__ float red[2];
    #pragma unroll
    for (int off = 32; off; off >>= 1) part += __shfl_down(part, off, 64);
    if ((threadIdx.x & 63) == 0) red[threadIdx.x >> 6] = part;
    __syncthreads();
    float d = rsqrtf(red[0] + red[1] + 1e-8f);
    out[(0 * O + o) * 128 + i] = f2bf(pc * d);
    out[(1 * O + o) * 128 + i] = f2bf(ps * d);
    out[(2 * O + o) * 128 + i] = f2bf(pr * d);
}

// ---------------- torgb weights: w_rgb[c,i] * s2[i] (no demod) ----------------
__global__ void k_rgb(const float* __restrict__ wrgb, const float* __restrict__ s2,
                      float* __restrict__ out)
{
    int t = threadIdx.x;
    if (t < 288) {
        int c = t / 96, i = t % 96;
        out[c * 96 + i] = wrgb[c * 96 + i] * s2[i];
    }
}

// ---------------- conv0: coarse modconv, MFMA, max over 9 ----------------
__launch_bounds__(256, 2)
__global__ void k_conv0(const unsigned short* __restrict__ xcat, const int* __restrict__ fn0,
                        const unsigned short* __restrict__ wm, const unsigned* __restrict__ zrow,
                        unsigned short* __restrict__ hconv0)
{
    int lane = threadIdx.x & 63;
    int wid = blockIdx.x * 4 + (threadIdx.x >> 6);  // 0..2047
    int tile = wid >> 1, ohalf = wid & 1;
    int fbase = tile * 32;
    int quad = lane >> 4, l15 = lane & 15;
    const char* xb = (const char*)xcat;
    const char* zr = (const char*)zrow;
    const char* wb = (const char*)wm;

    f32x4 runmax[2][4];
    #pragma unroll
    for (int mt = 0; mt < 2; ++mt)
        #pragma unroll
        for (int ot = 0; ot < 4; ++ot)
            #pragma unroll
            for (int r = 0; r < 4; ++r) runmax[mt][ot][r] = -1e30f;

    const int kbeg[3] = {0, 1, 5}, kend[3] = {1, 5, 9};
    for (int t = 0; t < 3; ++t) {
        bf16x8 b[4][4];
        #pragma unroll
        for (int ot = 0; ot < 4; ++ot)
            #pragma unroll
            for (int s = 0; s < 4; ++s) {
                int o = ohalf * 64 + ot * 16 + l15;
                b[ot][s] = *(const bf16x8*)(wb + (size_t)(((t * 128 + o) * 128 + s * 32 + quad * 8) * 2));
            }
        for (int k = kbeg[t]; k < kend[t]; ++k) {
            bf16x8 a[2][4];
            #pragma unroll
            for (int mt = 0; mt < 2; ++mt) {
                int fg = fbase + mt * 16 + l15;
                int idx = fn0[fg * 9 + k];
                const char* rp = ((unsigned)idx < FC) ? xb + (size_t)idx * 256 : zr;
                #pragma unroll
                for (int s = 0; s < 4; ++s)
                    a[mt][s] = *(const bf16x8*)(rp + s * 64 + quad * 16);
            }
            #pragma unroll
            for (int mt = 0; mt < 2; ++mt) {
                f32x4 acc[4];
                #pragma unroll
                for (int ot = 0; ot < 4; ++ot)
                    #pragma unroll
                    for (int r = 0; r < 4; ++r) acc[ot][r] = 0.f;
                #pragma unroll
                for (int s = 0; s < 4; ++s)
                    #pragma unroll
                    for (int ot = 0; ot < 4; ++ot)
                        acc[ot] = __builtin_amdgcn_mfma_f32_16x16x32_bf16(a[mt][s], b[ot][s], acc[ot], 0, 0, 0);
                #pragma unroll
                for (int ot = 0; ot < 4; ++ot)
                    #pragma unroll
                    for (int r = 0; r < 4; ++r)
                        runmax[mt][ot][r] = fmaxf(runmax[mt][ot][r], acc[ot][r]);
            }
        }
    }
    #pragma unroll
    for (int mt = 0; mt < 2; ++mt)
        #pragma unroll
        for (int ot = 0; ot < 4; ++ot)
            #pragma unroll
            for (int r = 0; r < 4; ++r) {
                int face = fbase + mt * 16 + quad * 4 + r;
                hconv0[face * 128 + ohalf * 64 + ot * 16 + l15] = f2bf(runmax[mt][ot][r]);
            }
}

// ---------------- smooth upsample + noise + act -> h1 bf16 [FF][128] ----------------
__global__ void k_upsample(const unsigned* __restrict__ hc, const int* __restrict__ fn1,
                           const int* __restrict__ pmap, const float* __restrict__ nco0,
                           const float* __restrict__ ns0p, const float* __restrict__ bias0,
                           unsigned* __restrict__ h1u)
{
    int c2 = threadIdx.x & 63;
    int f = blockIdx.x * 4 + (threadIdx.x >> 6);
    float a0 = 0.f, a1 = 0.f;
    #pragma unroll
    for (int j = 0; j < 9; ++j) {
        int g = fn1[f * 9 + j];
        if ((unsigned)g < FF) {
            unsigned u = hc[(size_t)pmap[g] * 64 + c2];
            a0 += bf2f((unsigned short)u);
            a1 += bf2f((unsigned short)(u >> 16));
        }
    }
    float nz = nco0[f] * ns0p[0];
    const float inv9 = 1.f / 9.f;
    a0 = actf(a0 * inv9 + nz + bias0[c2 * 2]);
    a1 = actf(a1 * inv9 + nz + bias0[c2 * 2 + 1]);
    h1u[(size_t)f * 64 + c2] = (unsigned)f2bf(a0) | ((unsigned)f2bf(a1) << 16);
}

// ---------------- conv1: fine modconv, MFMA, max over 9, noise+act -> d_out (f32) ----------------
__launch_bounds__(256, 2)
__global__ void k_conv1(const unsigned short* __restrict__ h1, const int* __restrict__ fn1,
                        const unsigned short* __restrict__ wm, const unsigned* __restrict__ zrow,
                        const float* __restrict__ nco1, const float* __restrict__ ns1p,
                        const float* __restrict__ bias1, float* __restrict__ hout)
{
    int lane = threadIdx.x & 63;
    int wid = blockIdx.x * 4 + (threadIdx.x >> 6);  // 0..4095
    int fbase = wid * 32;
    int quad = lane >> 4, l15 = lane & 15;
    const char* hb = (const char*)h1;
    const char* zr = (const char*)zrow;
    const char* wb = (const char*)wm;
    float ns1 = ns1p[0];

    f32x4 runmax[2][6];
    #pragma unroll
    for (int mt = 0; mt < 2; ++mt)
        #pragma unroll
        for (int ot = 0; ot < 6; ++ot)
            #pragma unroll
            for (int r = 0; r < 4; ++r) runmax[mt][ot][r] = -1e30f;

    const int kbeg[3] = {0, 1, 5}, kend[3] = {1, 5, 9};
    for (int t = 0; t < 3; ++t) {
        bf16x8 b[6][4];
        #pragma unroll
        for (int ot = 0; ot < 6; ++ot)
            #pragma unroll
            for (int s = 0; s < 4; ++s) {
                int o = ot * 16 + l15;
                b[ot][s] = *(const bf16x8*)(wb + (size_t)(((t * 96 + o) * 128 + s * 32 + quad * 8) * 2));
            }
        for (int k = kbeg[t]; k < kend[t]; ++k) {
            bf16x8 a[2][4];
            #pragma unroll
            for (int mt = 0; mt < 2; ++mt) {
                int fg = fbase + mt * 16 + l15;
                int idx = fn1[fg * 9 + k];
                const char* rp = ((unsigned)idx < FF) ? hb + (size_t)idx * 256 : zr;
                #pragma unroll
                for (int s = 0; s < 4; ++s)
                    a[mt][s] = *(const bf16x8*)(rp + s * 64 + quad * 16);
            }
            #pragma unroll
            for (int mt = 0; mt < 2; ++mt) {
                f32x4 acc[6];
                #pragma unroll
                for (int ot = 0; ot < 6; ++ot)
                    #pragma unroll
                    for (int r = 0; r < 4; ++r) acc[ot][r] = 0.f;
                #pragma unroll
                for (int s = 0; s < 4; ++s)
                    #pragma unroll
                    for (int ot = 0; ot < 6; ++ot)
                        acc[ot] = __builtin_amdgcn_mfma_f32_16x16x32_bf16(a[mt][s], b[ot][s], acc[ot], 0, 0, 0);
                #pragma unroll
                for (int ot = 0; ot < 6; ++ot)
                    #pragma unroll
                    for (int r = 0; r < 4; ++r)
                        runmax[mt][ot][r] = fmaxf(runmax[mt][ot][r], acc[ot][r]);
            }
        }
    }
    float bo[6];
    #pragma unroll
    for (int ot = 0; ot < 6; ++ot) bo[ot] = bias1[ot * 16 + l15];
    #pragma unroll
    for (int mt = 0; mt < 2; ++mt)
        #pragma unroll
        for (int r = 0; r < 4; ++r) {
            int face = fbase + mt * 16 + quad * 4 + r;
            float nz = nco1[face] * ns1;
            #pragma unroll
            for (int ot = 0; ot < 6; ++ot) {
                float v = actf(runmax[mt][ot][r] + nz + bo[ot]);
                hout[(size_t)face * 96 + ot * 16 + l15] = v;
            }
        }
}

// ---------------- torgb + img smooth-upsample -> d_out img part (f32) ----------------
__global__ void k_torgb(const float* __restrict__ h, const int* __restrict__ fn1,
                        const int* __restrict__ pmap, const float* __restrict__ img,
                        const float* __restrict__ wrgb, const float* __restrict__ brgb,
                        float* __restrict__ imgout)
{
    int f = blockIdx.x * 256 + threadIdx.x;
    float y0 = 0.f, y1 = 0.f, y2 = 0.f;
    int g0 = fn1[f * 9];
    if ((unsigned)g0 < FF) {
        const float* hr = h + (size_t)g0 * 96;
        #pragma unroll
        for (int i4 = 0; i4 < 24; ++i4) {
            f32x4 xv = *(const f32x4*)(hr + i4 * 4);
            f32x4 w0 = *(const f32x4*)(wrgb + i4 * 4);
            f32x4 w1 = *(const f32x4*)(wrgb + 96 + i4 * 4);
            f32x4 w2 = *(const f32x4*)(wrgb + 192 + i4 * 4);
            y0 += xv.x * w0.x + xv.y * w0.y + xv.z * w0.z + xv.w * w0.w;
            y1 += xv.x * w1.x + xv.y * w1.y + xv.z * w1.z + xv.w * w1.w;
            y2 += xv.x * w2.x + xv.y * w2.y + xv.z * w2.z + xv.w * w2.w;
        }
    }
    y0 = fminf(fmaxf(y0 + brgb[0], -CLAMP_V), CLAMP_V);
    y1 = fminf(fmaxf(y1 + brgb[1], -CLAMP_V), CLAMP_V);
    y2 = fminf(fmaxf(y2 + brgb[2], -CLAMP_V), CLAMP_V);
    float i0 = 0.f, i1 = 0.f, i2 = 0.f;
    #pragma unroll
    for (int j = 0; j < 9; ++j) {
        int g = fn1[f * 9 + j];
        if ((unsigned)g < FF) {
            const float* ir = img + (size_t)pmap[g] * 3;
            i0 += ir[0]; i1 += ir[1]; i2 += ir[2];
        }
    }
    const float inv9 = 1.f / 9.f;
    imgout[(size_t)f * 3 + 0] = i0 * inv9 + y0;
    imgout[(size_t)f * 3 + 1] = i1 * inv9 + y1;
    imgout[(size_t)f * 3 + 2] = i2 * inv9 + y2;
}

extern "C" void kernel_launch(void* const* d_in, const int* in_sizes, int n_in,
                              void* d_out, int out_size, void* d_ws, size_t ws_size,
                              hipStream_t stream) {
    const float* x     = (const float*)d_in[0];
    const float* sfeat = (const float*)d_in[1];
    const float* img   = (const float*)d_in[2];
    const float* wsv   = (const float*)d_in[3];
    const int* fn0     = (const int*)d_in[4];
    const int* fn1     = (const int*)d_in[5];
    const int* pmap    = (const int*)d_in[6];
    const float* a0w   = (const float*)d_in[9];
    const float* a0b   = (const float*)d_in[10];
    const float* wc0   = (const float*)d_in[11];
    const float* wsd0  = (const float*)d_in[12];
    const float* wcr0  = (const float*)d_in[13];
    const float* ns0   = (const float*)d_in[14];
    const float* bias0 = (const float*)d_in[15];
    const float* nco0  = (const float*)d_in[16];
    const float* a1w   = (const float*)d_in[17];
    const float* a1b   = (const float*)d_in[18];
    const float* wc1   = (const float*)d_in[19];
    const float* wsd1  = (const float*)d_in[20];
    const float* wcr1  = (const float*)d_in[21];
    const float* ns1   = (const float*)d_in[22];
    const float* bias1 = (const float*)d_in[23];
    const float* nco1  = (const float*)d_in[24];
    const float* a2w   = (const float*)d_in[25];
    const float* a2b   = (const float*)d_in[26];
    const float* wrgb  = (const float*)d_in[27];
    const float* brgb  = (const float*)d_in[28];

    char* wsb = (char*)d_ws;
    float* s0            = (float*)(wsb + 0);
    float* s1            = (float*)(wsb + 512);
    float* s2            = (float*)(wsb + 1024);
    float* wrgbmod       = (float*)(wsb + 1536);
    unsigned* zrow       = (unsigned*)(wsb + 4096);
    unsigned short* wm0  = (unsigned short*)(wsb + 8192);                   // 3*128*128*2 = 98304
    unsigned short* wm1  = (unsigned short*)(wsb + 8192 + 98304);           // 3*96*128*2  = 73728
    unsigned short* xcat = (unsigned short*)(wsb + 262144);                 // 32768*128*2 = 8388608
    unsigned short* hc0  = (unsigned short*)(wsb + 262144 + 8388608);       // 32768*128*2 = 8388608
    unsigned short* h1   = (unsigned short*)(wsb + 262144 + 2 * 8388608);   // 131072*128*2 = 33554432

    float* out_h   = (float*)d_out;
    float* out_img = out_h + (size_t)FF * 96;

    k_prep<<<1, 512, 0, stream>>>(wsv, a0w, a0b, a1w, a1b, a2w, a2b, s0, s1, s2, zrow);
    k_cvt<<<FC * 32 / 256, 256, 0, stream>>>(x, sfeat, (u16x4*)xcat);
    k_modw<<<128, 128, 0, stream>>>(wc0, wsd0, wcr0, s0, wm0, 128);
    k_modw<<<96, 128, 0, stream>>>(wc1, wsd1, wcr1, s1, wm1, 96);
    k_rgb<<<1, 320, 0, stream>>>(wrgb, s2, wrgbmod);
    k_conv0<<<512, 256, 0, stream>>>(xcat, fn0, wm0, zrow, hc0);
    k_upsample<<<FF / 4, 256, 0, stream>>>((const unsigned*)hc0, fn1, pmap, nco0, ns0, bias0, (unsigned*)h1);
    k_conv1<<<1024, 256, 0, stream>>>(h1, fn1, wm1, zrow, nco1, ns1, bias1, out_h);
    k_torgb<<<FF / 256, 256, 0, stream>>>(out_h, fn1, pmap, img, wrgbmod, brgb, out_img);
}

// Round 3
// 400.474 us; speedup vs baseline: 1.4348x; 1.4348x over previous
//
#include <hip/hip_runtime.h>

#define FC 32768
#define FF 131072
#define LRELU_SLOPE 0.2f
#define ACT_GAIN 1.4142135623730951f
#define CLAMP_V 256.0f

typedef __bf16 bf16x8 __attribute__((ext_vector_type(8)));
typedef float f32x4 __attribute__((ext_vector_type(4)));
typedef float f32x2 __attribute__((ext_vector_type(2)));
typedef unsigned u32x4 __attribute__((ext_vector_type(4)));
typedef unsigned short u16x4 __attribute__((ext_vector_type(4)));

static __device__ __forceinline__ unsigned short f2bf(float f) {
    unsigned u = __float_as_uint(f);
    u += 0x7FFFu + ((u >> 16) & 1u);
    return (unsigned short)(u >> 16);
}
static __device__ __forceinline__ float bf2f(unsigned short u) {
    return __uint_as_float(((unsigned)u) << 16);
}
static __device__ __forceinline__ float actf(float v) {
    v = (v < 0.f) ? v * LRELU_SLOPE : v;
    v *= ACT_GAIN;
    return fminf(fmaxf(v, -CLAMP_V), CLAMP_V);
}

// ---------------- styles (affine, f32) + zero-row init ----------------
__global__ void k_prep(const float* __restrict__ wsvec,
                       const float* __restrict__ a0w, const float* __restrict__ a0b,
                       const float* __restrict__ a1w, const float* __restrict__ a1b,
                       const float* __restrict__ a2w, const float* __restrict__ a2b,
                       float* __restrict__ s0, float* __restrict__ s1, float* __restrict__ s2,
                       unsigned* __restrict__ zrow)
{
    int t = threadIdx.x;
    if (t >= 352) {
        int z = t - 352;
        if (z < 64) zrow[z] = 0u;
        return;
    }
    int level, o;
    const float *W, *bptr; float* out;
    if (t < 128)       { level = 0; o = t;       W = a0w; bptr = a0b; out = s0; }
    else if (t < 256)  { level = 1; o = t - 128; W = a1w; bptr = a1b; out = s1; }
    else               { level = 2; o = t - 256; W = a2w; bptr = a2b; out = s2; }
    const float* wrow = wsvec + level * 512;
    const float* Wr = W + o * 512;
    float acc = 0.f;
    for (int d = 0; d < 512; ++d) acc += wrow[d] * Wr[d];
    float v = acc * 0.04419417382415922f + bptr[o];
    if (level == 2) v *= 0.10206207261596577f;  // 1/sqrt(96) torgb weight gain
    out[o] = v;
}

// ---------------- concat(x, shape_feat) f32 -> bf16 [FC][128] ----------------
__global__ void k_cvt(const float* __restrict__ x, const float* __restrict__ sf,
                      u16x4* __restrict__ xcat)
{
    int gid = blockIdx.x * 256 + threadIdx.x;
    int f = gid >> 5;
    int c4 = (gid & 31) * 4;
    f32x4 v;
    if (c4 < 96) v = *(const f32x4*)(x + (size_t)f * 96 + c4);
    else         v = *(const f32x4*)(sf + (size_t)f * 32 + (c4 - 96));
    u16x4 o;
    o.x = f2bf(v.x); o.y = f2bf(v.y); o.z = f2bf(v.z); o.w = f2bf(v.w);
    xcat[gid] = o;
}

// ---------------- modulate + demodulate weights -> bf16 [3][O][128] ----------------
__global__ void k_modw(const float* __restrict__ wc, const float* __restrict__ wsd,
                       const float* __restrict__ wcr, const float* __restrict__ s,
                       unsigned short* __restrict__ out, int O)
{
    int o = blockIdx.x;
    int i = threadIdx.x;
    float sv = s[i];
    float pc = wc[o * 128 + i] * sv;
    float ps = wsd[o * 128 + i] * sv;
    float pr = wcr[o * 128 + i] * sv;
    float part = pc * pc + 4.f * ps * ps + 4.f * pr * pr;
    __shared__ float red[2];
    #pragma unroll
    for (int off = 32; off; off >>= 1) part += __shfl_down(part, off, 64);
    if ((threadIdx.x & 63) == 0) red[threadIdx.x >> 6] = part;
    __syncthreads();
    float d = rsqrtf(red[0] + red[1] + 1e-8f);
    out[(0 * O + o) * 128 + i] = f2bf(pc * d);
    out[(1 * O + o) * 128 + i] = f2bf(ps * d);
    out[(2 * O + o) * 128 + i] = f2bf(pr * d);
}

// ---------------- torgb weights ----------------
__global__ void k_rgb(const float* __restrict__ wrgb, const float* __restrict__ s2,
                      float* __restrict__ out)
{
    int t = threadIdx.x;
    if (t < 288) {
        int c = t / 96, i = t % 96;
        out[c * 96 + i] = wrgb[c * 96 + i] * s2[i];
    }
}

// ---------------- composed index: cidx = (fn1 valid) ? pmap[fn1] : -1 ----------------
__global__ void k_cidx(const int* __restrict__ fn1, const int* __restrict__ pmap,
                       int* __restrict__ cidx)
{
    int gid = blockIdx.x * 256 + threadIdx.x;  // FF*9
    int g = fn1[gid];
    cidx[gid] = ((unsigned)g < FF) ? pmap[g] : -1;
}

// ---------------- conv0: coarse modconv, MFMA, max over 9 ----------------
__launch_bounds__(256, 2)
__global__ void k_conv0(const unsigned short* __restrict__ xcat, const int* __restrict__ fn0,
                        const unsigned short* __restrict__ wm, const unsigned* __restrict__ zrow,
                        unsigned short* __restrict__ hconv0)
{
    int lane = threadIdx.x & 63;
    int wid = blockIdx.x * 4 + (threadIdx.x >> 6);
    int tile = wid >> 1, ohalf = wid & 1;
    int fbase = tile * 32;
    int quad = lane >> 4, l15 = lane & 15;
    const char* xb = (const char*)xcat;
    const char* zr = (const char*)zrow;
    const char* wb = (const char*)wm;

    f32x4 runmax[2][4];
    #pragma unroll
    for (int mt = 0; mt < 2; ++mt)
        #pragma unroll
        for (int ot = 0; ot < 4; ++ot)
            #pragma unroll
            for (int r = 0; r < 4; ++r) runmax[mt][ot][r] = -1e30f;

    const int kbeg[3] = {0, 1, 5}, kend[3] = {1, 5, 9};
    for (int t = 0; t < 3; ++t) {
        bf16x8 b[4][4];
        #pragma unroll
        for (int ot = 0; ot < 4; ++ot)
            #pragma unroll
            for (int s = 0; s < 4; ++s) {
                int o = ohalf * 64 + ot * 16 + l15;
                b[ot][s] = *(const bf16x8*)(wb + (size_t)(((t * 128 + o) * 128 + s * 32 + quad * 8) * 2));
            }
        for (int k = kbeg[t]; k < kend[t]; ++k) {
            bf16x8 a[2][4];
            #pragma unroll
            for (int mt = 0; mt < 2; ++mt) {
                int fg = fbase + mt * 16 + l15;
                int idx = fn0[fg * 9 + k];
                const char* rp = ((unsigned)idx < FC) ? xb + (size_t)idx * 256 : zr;
                #pragma unroll
                for (int s = 0; s < 4; ++s)
                    a[mt][s] = *(const bf16x8*)(rp + s * 64 + quad * 16);
            }
            #pragma unroll
            for (int mt = 0; mt < 2; ++mt) {
                f32x4 acc[4];
                #pragma unroll
                for (int ot = 0; ot < 4; ++ot)
                    #pragma unroll
                    for (int r = 0; r < 4; ++r) acc[ot][r] = 0.f;
                #pragma unroll
                for (int s = 0; s < 4; ++s)
                    #pragma unroll
                    for (int ot = 0; ot < 4; ++ot)
                        acc[ot] = __builtin_amdgcn_mfma_f32_16x16x32_bf16(a[mt][s], b[ot][s], acc[ot], 0, 0, 0);
                #pragma unroll
                for (int ot = 0; ot < 4; ++ot)
                    #pragma unroll
                    for (int r = 0; r < 4; ++r)
                        runmax[mt][ot][r] = fmaxf(runmax[mt][ot][r], acc[ot][r]);
            }
        }
    }
    #pragma unroll
    for (int mt = 0; mt < 2; ++mt)
        #pragma unroll
        for (int ot = 0; ot < 4; ++ot)
            #pragma unroll
            for (int r = 0; r < 4; ++r) {
                int face = fbase + mt * 16 + quad * 4 + r;
                hconv0[face * 128 + ohalf * 64 + ot * 16 + l15] = f2bf(runmax[mt][ot][r]);
            }
}

// ---------------- smooth upsample + noise + act -> h1 bf16 [FF][128] ----------------
__global__ void k_upsample(const unsigned* __restrict__ hc, const int* __restrict__ cidx,
                           const float* __restrict__ nco0,
                           const float* __restrict__ ns0p, const float* __restrict__ bias0,
                           unsigned* __restrict__ h1u, const unsigned* __restrict__ zrow)
{
    int c2 = threadIdx.x & 63;
    int f = blockIdx.x * 4 + (threadIdx.x >> 6);
    int id[9];
    #pragma unroll
    for (int j = 0; j < 9; ++j) id[j] = cidx[f * 9 + j];
    unsigned v[9];
    #pragma unroll
    for (int j = 0; j < 9; ++j) {
        const unsigned* p = (id[j] >= 0) ? (hc + (size_t)id[j] * 64) : zrow;
        v[j] = p[c2];
    }
    float a0 = 0.f, a1 = 0.f;
    #pragma unroll
    for (int j = 0; j < 9; ++j) {
        a0 += bf2f((unsigned short)v[j]);
        a1 += bf2f((unsigned short)(v[j] >> 16));
    }
    float nz = nco0[f] * ns0p[0];
    const float inv9 = 1.f / 9.f;
    a0 = actf(a0 * inv9 + nz + bias0[c2 * 2]);
    a1 = actf(a1 * inv9 + nz + bias0[c2 * 2 + 1]);
    h1u[(size_t)f * 64 + c2] = (unsigned)f2bf(a0) | ((unsigned)f2bf(a1) << 16);
}

// ---------------- gemm1: y_t = h1 . W_t^T, dense -> bf16 y[3][FF][96] ----------------
__launch_bounds__(256, 2)
__global__ void k_gemm1(const unsigned short* __restrict__ h1, const unsigned short* __restrict__ wm,
                        unsigned* __restrict__ ybase)
{
    __shared__ unsigned short sm[4][32 * 104];  // per wave: 32 faces x (96+8 pad) u16
    int lane = threadIdx.x & 63;
    int w = threadIdx.x >> 6;
    int fbase = (blockIdx.x * 4 + w) * 32;
    int quad = lane >> 4, l15 = lane & 15;
    const char* hb = (const char*)h1;
    const char* wb = (const char*)wm;
    unsigned short* lds = sm[w];

    bf16x8 a[2][4];
    #pragma unroll
    for (int mt = 0; mt < 2; ++mt)
        #pragma unroll
        for (int s = 0; s < 4; ++s)
            a[mt][s] = *(const bf16x8*)(hb + (size_t)(fbase + mt * 16 + l15) * 256 + s * 64 + quad * 16);

    for (int t = 0; t < 3; ++t) {
        bf16x8 b[6][4];
        #pragma unroll
        for (int ot = 0; ot < 6; ++ot)
            #pragma unroll
            for (int s = 0; s < 4; ++s)
                b[ot][s] = *(const bf16x8*)(wb + (size_t)(((t * 96 + ot * 16 + l15) * 128 + s * 32 + quad * 8) * 2));
        f32x4 acc[2][6];
        #pragma unroll
        for (int mt = 0; mt < 2; ++mt)
            #pragma unroll
            for (int ot = 0; ot < 6; ++ot)
                #pragma unroll
                for (int r = 0; r < 4; ++r) acc[mt][ot][r] = 0.f;
        #pragma unroll
        for (int s = 0; s < 4; ++s)
            #pragma unroll
            for (int mt = 0; mt < 2; ++mt)
                #pragma unroll
                for (int ot = 0; ot < 6; ++ot)
                    acc[mt][ot] = __builtin_amdgcn_mfma_f32_16x16x32_bf16(a[mt][s], b[ot][s], acc[mt][ot], 0, 0, 0);
        #pragma unroll
        for (int mt = 0; mt < 2; ++mt)
            #pragma unroll
            for (int ot = 0; ot < 6; ++ot)
                #pragma unroll
                for (int r = 0; r < 4; ++r)
                    lds[(mt * 16 + quad * 4 + r) * 104 + ot * 16 + l15] = f2bf(acc[mt][ot][r]);
        unsigned* yt = ybase + (size_t)t * FF * 48;
        #pragma unroll
        for (int it = 0; it < 6; ++it) {
            int ci = it * 64 + lane;
            int face = ci / 12;
            int off = ci - face * 12;
            u32x4 val = *(const u32x4*)(lds + face * 104 + off * 8);
            *(u32x4*)(yt + (size_t)(fbase + face) * 48 + off * 4) = val;
        }
    }
}

// ---------------- gather1: out[f] = act(max_k y_{t(k)}[fn1[f,k]] + noise + bias) ----------------
__global__ void k_gather1(const char* __restrict__ yc, const int* __restrict__ fn1,
                          const char* __restrict__ zr,
                          const float* __restrict__ nco1, const float* __restrict__ ns1p,
                          const float* __restrict__ bias1, float* __restrict__ hout)
{
    int gid = blockIdx.x * 256 + threadIdx.x;  // FF*48 threads, u32 (2ch) each
    int face = gid / 48;
    int c = gid - face * 48;
    const char* ys = yc + (size_t)FF * 192;
    const char* yr = yc + (size_t)2 * FF * 192;
    int id[9];
    #pragma unroll
    for (int j = 0; j < 9; ++j) id[j] = fn1[face * 9 + j];
    unsigned v[9];
    #pragma unroll
    for (int j = 0; j < 9; ++j) {
        const char* base = (j == 0) ? yc : (j < 5 ? ys : yr);
        const char* p = ((unsigned)id[j] < FF) ? base + (size_t)id[j] * 192 : zr;
        v[j] = *(const unsigned*)(p + c * 4);
    }
    float m0 = bf2f((unsigned short)v[0]);
    float m1 = bf2f((unsigned short)(v[0] >> 16));
    #pragma unroll
    for (int j = 1; j < 9; ++j) {
        m0 = fmaxf(m0, bf2f((unsigned short)v[j]));
        m1 = fmaxf(m1, bf2f((unsigned short)(v[j] >> 16)));
    }
    float nz = nco1[face] * ns1p[0];
    f32x2 o;
    o.x = actf(m0 + nz + bias1[c * 2]);
    o.y = actf(m1 + nz + bias1[c * 2 + 1]);
    *(f32x2*)(hout + (size_t)face * 96 + c * 2) = o;
}

// ---------------- torgb + img smooth-upsample (wave per face) ----------------
__global__ void k_torgb(const float* __restrict__ h, const int* __restrict__ fn1,
                        const int* __restrict__ cidx, const float* __restrict__ img,
                        const float* __restrict__ wrgb, const float* __restrict__ brgb,
                        float* __restrict__ imgout)
{
    int lane = threadIdx.x & 63;
    int f = blockIdx.x * 4 + (threadIdx.x >> 6);
    float d0 = 0.f, d1 = 0.f, d2 = 0.f;
    int g0 = fn1[f * 9];
    if (lane < 48 && (unsigned)g0 < FF) {
        f32x2 hv = *(const f32x2*)(h + (size_t)g0 * 96 + lane * 2);
        d0 = hv.x * wrgb[lane * 2] + hv.y * wrgb[lane * 2 + 1];
        d1 = hv.x * wrgb[96 + lane * 2] + hv.y * wrgb[96 + lane * 2 + 1];
        d2 = hv.x * wrgb[192 + lane * 2] + hv.y * wrgb[192 + lane * 2 + 1];
    }
    float i0 = 0.f, i1 = 0.f, i2 = 0.f;
    if (lane >= 48 && lane < 57) {
        int id = cidx[f * 9 + (lane - 48)];
        if (id >= 0) {
            const float* ir = img + (size_t)id * 3;
            i0 = ir[0]; i1 = ir[1]; i2 = ir[2];
        }
    }
    #pragma unroll
    for (int off = 32; off; off >>= 1) {
        d0 += __shfl_down(d0, off, 64);
        d1 += __shfl_down(d1, off, 64);
        d2 += __shfl_down(d2, off, 64);
        i0 += __shfl_down(i0, off, 64);
        i1 += __shfl_down(i1, off, 64);
        i2 += __shfl_down(i2, off, 64);
    }
    if (lane == 0) {
        const float inv9 = 1.f / 9.f;
        float y0 = fminf(fmaxf(d0 + brgb[0], -CLAMP_V), CLAMP_V);
        float y1 = fminf(fmaxf(d1 + brgb[1], -CLAMP_V), CLAMP_V);
        float y2 = fminf(fmaxf(d2 + brgb[2], -CLAMP_V), CLAMP_V);
        imgout[(size_t)f * 3 + 0] = i0 * inv9 + y0;
        imgout[(size_t)f * 3 + 1] = i1 * inv9 + y1;
        imgout[(size_t)f * 3 + 2] = i2 * inv9 + y2;
    }
}

extern "C" void kernel_launch(void* const* d_in, const int* in_sizes, int n_in,
                              void* d_out, int out_size, void* d_ws, size_t ws_size,
                              hipStream_t stream) {
    const float* x     = (const float*)d_in[0];
    const float* sfeat = (const float*)d_in[1];
    const float* img   = (const float*)d_in[2];
    const float* wsv   = (const float*)d_in[3];
    const int* fn0     = (const int*)d_in[4];
    const int* fn1     = (const int*)d_in[5];
    const int* pmap    = (const int*)d_in[6];
    const float* a0w   = (const float*)d_in[9];
    const float* a0b   = (const float*)d_in[10];
    const float* wc0   = (const float*)d_in[11];
    const float* wsd0  = (const float*)d_in[12];
    const float* wcr0  = (const float*)d_in[13];
    const float* ns0   = (const float*)d_in[14];
    const float* bias0 = (const float*)d_in[15];
    const float* nco0  = (const float*)d_in[16];
    const float* a1w   = (const float*)d_in[17];
    const float* a1b   = (const float*)d_in[18];
    const float* wc1   = (const float*)d_in[19];
    const float* wsd1  = (const float*)d_in[20];
    const float* wcr1  = (const float*)d_in[21];
    const float* ns1   = (const float*)d_in[22];
    const float* bias1 = (const float*)d_in[23];
    const float* nco1  = (const float*)d_in[24];
    const float* a2w   = (const float*)d_in[25];
    const float* a2b   = (const float*)d_in[26];
    const float* wrgb  = (const float*)d_in[27];
    const float* brgb  = (const float*)d_in[28];

    char* wsb = (char*)d_ws;
    float* s0            = (float*)(wsb + 0);
    float* s1            = (float*)(wsb + 512);
    float* s2            = (float*)(wsb + 1024);
    float* wrgbmod       = (float*)(wsb + 1536);
    unsigned* zrow       = (unsigned*)(wsb + 4096);
    unsigned short* wm0  = (unsigned short*)(wsb + 8192);
    unsigned short* wm1  = (unsigned short*)(wsb + 8192 + 98304);
    unsigned short* h1   = (unsigned short*)(wsb + 262144);                                  // 33.55 MB
    int* cidx            = (int*)(wsb + 262144 + 33554432);                                  // 4.72 MB
    unsigned short* xcat = (unsigned short*)(wsb + 262144 + 33554432 + 4718592);             // 8.39 MB
    unsigned short* hc0  = (unsigned short*)(wsb + 262144 + 33554432 + 4718592 + 8388608);   // 8.39 MB
    unsigned* ybase      = (unsigned*)(wsb + 262144 + 33554432 + 4718592);                   // 37.75 MB, overlaps xcat+hc0 (dead)

    float* out_h   = (float*)d_out;
    float* out_img = out_h + (size_t)FF * 96;

    k_prep<<<1, 512, 0, stream>>>(wsv, a0w, a0b, a1w, a1b, a2w, a2b, s0, s1, s2, zrow);
    k_cvt<<<FC * 32 / 256, 256, 0, stream>>>(x, sfeat, (u16x4*)xcat);
    k_modw<<<128, 128, 0, stream>>>(wc0, wsd0, wcr0, s0, wm0, 128);
    k_modw<<<96, 128, 0, stream>>>(wc1, wsd1, wcr1, s1, wm1, 96);
    k_rgb<<<1, 320, 0, stream>>>(wrgb, s2, wrgbmod);
    k_cidx<<<FF * 9 / 256, 256, 0, stream>>>(fn1, pmap, cidx);
    k_conv0<<<512, 256, 0, stream>>>(xcat, fn0, wm0, zrow, hc0);
    k_upsample<<<FF / 4, 256, 0, stream>>>((const unsigned*)hc0, cidx, nco0, ns0, bias0, (unsigned*)h1, zrow);
    k_gemm1<<<FF / 128, 256, 0, stream>>>(h1, wm1, ybase);
    k_gather1<<<FF * 48 / 256, 256, 0, stream>>>((const char*)ybase, fn1, (const char*)zrow, nco1, ns1, bias1, out_h);
    k_torgb<<<FF / 4, 256, 0, stream>>>(out_h, fn1, cidx, img, wrgbmod, brgb, out_img);
}

// Round 5
// 373.123 us; speedup vs baseline: 1.5400x; 1.0733x over previous
//
#include <hip/hip_runtime.h>

#define FC 32768
#define FF 131072
#define LRELU_SLOPE 0.2f
#define ACT_GAIN 1.4142135623730951f
#define CLAMP_V 256.0f

typedef __bf16 bf16x8 __attribute__((ext_vector_type(8)));
typedef float f32x4 __attribute__((ext_vector_type(4)));
typedef float f32x2 __attribute__((ext_vector_type(2)));
typedef unsigned u32x4 __attribute__((ext_vector_type(4)));
typedef unsigned short u16x4 __attribute__((ext_vector_type(4)));

static __device__ __forceinline__ unsigned short f2bf(float f) {
    unsigned u = __float_as_uint(f);
    u += 0x7FFFu + ((u >> 16) & 1u);
    return (unsigned short)(u >> 16);
}
static __device__ __forceinline__ float bf2f(unsigned short u) {
    return __uint_as_float(((unsigned)u) << 16);
}
static __device__ __forceinline__ float actf(float v) {
    v = (v < 0.f) ? v * LRELU_SLOPE : v;
    v *= ACT_GAIN;
    return fminf(fmaxf(v, -CLAMP_V), CLAMP_V);
}

// ---------------- styles (affine, f32) + zero-row init ----------------
__global__ void k_prep(const float* __restrict__ wsvec,
                       const float* __restrict__ a0w, const float* __restrict__ a0b,
                       const float* __restrict__ a1w, const float* __restrict__ a1b,
                       const float* __restrict__ a2w, const float* __restrict__ a2b,
                       float* __restrict__ s0, float* __restrict__ s1, float* __restrict__ s2,
                       unsigned* __restrict__ zrow)
{
    int t = threadIdx.x;
    if (t >= 352) {
        int z = t - 352;
        if (z < 64) zrow[z] = 0u;
        return;
    }
    int level, o;
    const float *W, *bptr; float* out;
    if (t < 128)       { level = 0; o = t;       W = a0w; bptr = a0b; out = s0; }
    else if (t < 256)  { level = 1; o = t - 128; W = a1w; bptr = a1b; out = s1; }
    else               { level = 2; o = t - 256; W = a2w; bptr = a2b; out = s2; }
    const float* wrow = wsvec + level * 512;
    const float* Wr = W + o * 512;
    float acc = 0.f;
    for (int d = 0; d < 512; ++d) acc += wrow[d] * Wr[d];
    float v = acc * 0.04419417382415922f + bptr[o];
    if (level == 2) v *= 0.10206207261596577f;  // 1/sqrt(96) torgb weight gain
    out[o] = v;
}

// ---------------- fused: cvt (concat->bf16) + composed index ----------------
__global__ void k_misc(const float* __restrict__ x, const float* __restrict__ sf,
                       u16x4* __restrict__ xcat,
                       const int* __restrict__ fn1, const int* __restrict__ pmap,
                       int* __restrict__ cidx)
{
    int b = blockIdx.x;
    if (b < FC * 32 / 256) {
        int gid = b * 256 + threadIdx.x;
        int f = gid >> 5;
        int c4 = (gid & 31) * 4;
        f32x4 v;
        if (c4 < 96) v = *(const f32x4*)(x + (size_t)f * 96 + c4);
        else         v = *(const f32x4*)(sf + (size_t)f * 32 + (c4 - 96));
        u16x4 o;
        o.x = f2bf(v.x); o.y = f2bf(v.y); o.z = f2bf(v.z); o.w = f2bf(v.w);
        xcat[gid] = o;
    } else {
        int gid = (b - FC * 32 / 256) * 256 + threadIdx.x;  // FF*9
        int g = fn1[gid];
        cidx[gid] = ((unsigned)g < FF) ? pmap[g] : -1;
    }
}

// ---------------- modulate + demodulate weights -> bf16 [3][O][128] ----------------
__global__ void k_modw(const float* __restrict__ wc, const float* __restrict__ wsd,
                       const float* __restrict__ wcr, const float* __restrict__ s,
                       unsigned short* __restrict__ out, int O)
{
    int o = blockIdx.x;
    int i = threadIdx.x;
    float sv = s[i];
    float pc = wc[o * 128 + i] * sv;
    float ps = wsd[o * 128 + i] * sv;
    float pr = wcr[o * 128 + i] * sv;
    float part = pc * pc + 4.f * ps * ps + 4.f * pr * pr;
    __shared__ float red[2];
    #pragma unroll
    for (int off = 32; off; off >>= 1) part += __shfl_down(part, off, 64);
    if ((threadIdx.x & 63) == 0) red[threadIdx.x >> 6] = part;
    __syncthreads();
    float d = rsqrtf(red[0] + red[1] + 1e-8f);
    out[(0 * O + o) * 128 + i] = f2bf(pc * d);
    out[(1 * O + o) * 128 + i] = f2bf(ps * d);
    out[(2 * O + o) * 128 + i] = f2bf(pr * d);
}

// ---------------- torgb weights (f32, style-scaled) ----------------
__global__ void k_rgbw(const float* __restrict__ wrgb, const float* __restrict__ s2,
                       float* __restrict__ out)
{
    int t = threadIdx.x;
    if (t < 288) {
        int c = t / 96, i = t % 96;
        out[c * 96 + i] = wrgb[c * 96 + i] * s2[i];
    }
}

// ---------------- gemm0: y0_t = xcat . W0_t^T  -> bf16 y0[3][FC][128] ----------------
__launch_bounds__(256, 2)
__global__ void k_gemm0(const unsigned short* __restrict__ xcat, const unsigned short* __restrict__ wm,
                        unsigned* __restrict__ y0)
{
    __shared__ unsigned short sm[4][32 * 136];  // per wave: 32 faces x (128+8 pad) u16
    int lane = threadIdx.x & 63;
    int w = threadIdx.x >> 6;
    int fbase = (blockIdx.x * 4 + w) * 32;
    int quad = lane >> 4, l15 = lane & 15;
    const char* hb = (const char*)xcat;
    const char* wb = (const char*)wm;
    unsigned short* lds = sm[w];

    bf16x8 a[2][4];
    #pragma unroll
    for (int mt = 0; mt < 2; ++mt)
        #pragma unroll
        for (int s = 0; s < 4; ++s)
            a[mt][s] = *(const bf16x8*)(hb + (size_t)(fbase + mt * 16 + l15) * 256 + s * 64 + quad * 16);

    for (int t = 0; t < 3; ++t) {
        bf16x8 b[8][4];
        #pragma unroll
        for (int ot = 0; ot < 8; ++ot)
            #pragma unroll
            for (int s = 0; s < 4; ++s)
                b[ot][s] = *(const bf16x8*)(wb + (size_t)(((t * 128 + ot * 16 + l15) * 128 + s * 32 + quad * 8) * 2));
        f32x4 acc[2][8];
        #pragma unroll
        for (int mt = 0; mt < 2; ++mt)
            #pragma unroll
            for (int ot = 0; ot < 8; ++ot)
                #pragma unroll
                for (int r = 0; r < 4; ++r) acc[mt][ot][r] = 0.f;
        #pragma unroll
        for (int s = 0; s < 4; ++s)
            #pragma unroll
            for (int mt = 0; mt < 2; ++mt)
                #pragma unroll
                for (int ot = 0; ot < 8; ++ot)
                    acc[mt][ot] = __builtin_amdgcn_mfma_f32_16x16x32_bf16(a[mt][s], b[ot][s], acc[mt][ot], 0, 0, 0);
        #pragma unroll
        for (int mt = 0; mt < 2; ++mt)
            #pragma unroll
            for (int ot = 0; ot < 8; ++ot)
                #pragma unroll
                for (int r = 0; r < 4; ++r)
                    lds[(mt * 16 + quad * 4 + r) * 136 + ot * 16 + l15] = f2bf(acc[mt][ot][r]);
        unsigned* yt = y0 + (size_t)t * FC * 64;
        #pragma unroll
        for (int it = 0; it < 8; ++it) {
            int ci = it * 64 + lane;
            int face = ci >> 4;
            int off = ci & 15;
            u32x4 val = *(const u32x4*)(lds + face * 136 + off * 8);
            *(u32x4*)(yt + (size_t)(fbase + face) * 64 + off * 4) = val;
        }
    }
}

// ---------------- gather0: hc0[g] = max_k y0_{t(k)}[fn0[g,k]] (packed bf16x2) ----------------
__global__ void k_gather0(const unsigned* __restrict__ y0, const int* __restrict__ fn0,
                          const unsigned* __restrict__ zrow, unsigned* __restrict__ hc0)
{
    int gid = blockIdx.x * 256 + threadIdx.x;  // FC*64
    int g = gid >> 6;
    int c = gid & 63;
    int id[9];
    #pragma unroll
    for (int j = 0; j < 9; ++j) id[j] = fn0[g * 9 + j];
    unsigned v[9];
    #pragma unroll
    for (int j = 0; j < 9; ++j) {
        int t = (j == 0) ? 0 : (j < 5 ? 1 : 2);
        const unsigned* p = ((unsigned)id[j] < FC) ? (y0 + (size_t)t * FC * 64 + (size_t)id[j] * 64) : zrow;
        v[j] = p[c];
    }
    float m0 = bf2f((unsigned short)v[0]);
    float m1 = bf2f((unsigned short)(v[0] >> 16));
    #pragma unroll
    for (int j = 1; j < 9; ++j) {
        m0 = fmaxf(m0, bf2f((unsigned short)v[j]));
        m1 = fmaxf(m1, bf2f((unsigned short)(v[j] >> 16)));
    }
    hc0[gid] = (unsigned)f2bf(m0) | ((unsigned)f2bf(m1) << 16);
}

// ---------------- smooth upsample + noise + act -> h1 bf16 [FF][128] ----------------
__global__ void k_upsample(const unsigned* __restrict__ hc, const int* __restrict__ cidx,
                           const float* __restrict__ nco0,
                           const float* __restrict__ ns0p, const float* __restrict__ bias0,
                           unsigned* __restrict__ h1u, const unsigned* __restrict__ zrow)
{
    int c2 = threadIdx.x & 63;
    int f = blockIdx.x * 4 + (threadIdx.x >> 6);
    int id[9];
    #pragma unroll
    for (int j = 0; j < 9; ++j) id[j] = cidx[f * 9 + j];
    unsigned v[9];
    #pragma unroll
    for (int j = 0; j < 9; ++j) {
        const unsigned* p = (id[j] >= 0) ? (hc + (size_t)id[j] * 64) : zrow;
        v[j] = p[c2];
    }
    float a0 = 0.f, a1 = 0.f;
    #pragma unroll
    for (int j = 0; j < 9; ++j) {
        a0 += bf2f((unsigned short)v[j]);
        a1 += bf2f((unsigned short)(v[j] >> 16));
    }
    float nz = nco0[f] * ns0p[0];
    const float inv9 = 1.f / 9.f;
    a0 = actf(a0 * inv9 + nz + bias0[c2 * 2]);
    a1 = actf(a1 * inv9 + nz + bias0[c2 * 2 + 1]);
    h1u[(size_t)f * 64 + c2] = (unsigned)f2bf(a0) | ((unsigned)f2bf(a1) << 16);
}

// ---------------- gemm1 half: y_t[:, half*48:half*48+48] -> bf16 yh[3][FF][48] ----------------
__launch_bounds__(256, 2)
__global__ void k_gemm1h(const unsigned short* __restrict__ h1, const unsigned short* __restrict__ wm,
                         unsigned* __restrict__ yh, int half)
{
    __shared__ unsigned short sm[4][32 * 56];  // per wave: 32 faces x (48+8 pad) u16
    int lane = threadIdx.x & 63;
    int w = threadIdx.x >> 6;
    int fbase = (blockIdx.x * 4 + w) * 32;
    int quad = lane >> 4, l15 = lane & 15;
    const char* hb = (const char*)h1;
    const char* wb = (const char*)wm;
    unsigned short* lds = sm[w];

    bf16x8 a[2][4];
    #pragma unroll
    for (int mt = 0; mt < 2; ++mt)
        #pragma unroll
        for (int s = 0; s < 4; ++s)
            a[mt][s] = *(const bf16x8*)(hb + (size_t)(fbase + mt * 16 + l15) * 256 + s * 64 + quad * 16);

    for (int t = 0; t < 3; ++t) {
        bf16x8 b[3][4];
        #pragma unroll
        for (int ot = 0; ot < 3; ++ot)
            #pragma unroll
            for (int s = 0; s < 4; ++s)
                b[ot][s] = *(const bf16x8*)(wb + (size_t)(((t * 96 + half * 48 + ot * 16 + l15) * 128 + s * 32 + quad * 8) * 2));
        f32x4 acc[2][3];
        #pragma unroll
        for (int mt = 0; mt < 2; ++mt)
            #pragma unroll
            for (int ot = 0; ot < 3; ++ot)
                #pragma unroll
                for (int r = 0; r < 4; ++r) acc[mt][ot][r] = 0.f;
        #pragma unroll
        for (int s = 0; s < 4; ++s)
            #pragma unroll
            for (int mt = 0; mt < 2; ++mt)
                #pragma unroll
                for (int ot = 0; ot < 3; ++ot)
                    acc[mt][ot] = __builtin_amdgcn_mfma_f32_16x16x32_bf16(a[mt][s], b[ot][s], acc[mt][ot], 0, 0, 0);
        #pragma unroll
        for (int mt = 0; mt < 2; ++mt)
            #pragma unroll
            for (int ot = 0; ot < 3; ++ot)
                #pragma unroll
                for (int r = 0; r < 4; ++r)
                    lds[(mt * 16 + quad * 4 + r) * 56 + ot * 16 + l15] = f2bf(acc[mt][ot][r]);
        unsigned* yt = yh + (size_t)t * FF * 24;
        #pragma unroll
        for (int it = 0; it < 3; ++it) {
            int ci = it * 64 + lane;
            int face = ci / 6;
            int off = ci - face * 6;
            u32x4 val = *(const u32x4*)(lds + face * 56 + off * 8);
            *(u32x4*)(yt + (size_t)(fbase + face) * 24 + off * 4) = val;
        }
    }
}

// ---------------- gather1 half: out_h[:, half] = act(max_k yh_{t(k)}[fn1] + nz + b) ----------------
__global__ void k_gather1h(const unsigned* __restrict__ yh, const int* __restrict__ fn1,
                           const unsigned* __restrict__ zrow,
                           const float* __restrict__ nco1, const float* __restrict__ ns1p,
                           const float* __restrict__ bias1, float* __restrict__ hout, int half)
{
    int gid = blockIdx.x * 256 + threadIdx.x;  // FF*24 threads, u32 (2ch) each
    int face = gid / 24;
    int c = gid - face * 24;
    int id[9];
    #pragma unroll
    for (int j = 0; j < 9; ++j) id[j] = fn1[face * 9 + j];
    unsigned v[9];
    #pragma unroll
    for (int j = 0; j < 9; ++j) {
        int t = (j == 0) ? 0 : (j < 5 ? 1 : 2);
        const unsigned* p = ((unsigned)id[j] < FF) ? (yh + (size_t)t * FF * 24 + (size_t)id[j] * 24) : zrow;
        v[j] = p[c];
    }
    float m0 = bf2f((unsigned short)v[0]);
    float m1 = bf2f((unsigned short)(v[0] >> 16));
    #pragma unroll
    for (int j = 1; j < 9; ++j) {
        m0 = fmaxf(m0, bf2f((unsigned short)v[j]));
        m1 = fmaxf(m1, bf2f((unsigned short)(v[j] >> 16)));
    }
    float nz = nco1[face] * ns1p[0];
    int ch = half * 48 + c * 2;
    f32x2 o;
    o.x = actf(m0 + nz + bias1[ch]);
    o.y = actf(m1 + nz + bias1[ch + 1]);
    *(f32x2*)(hout + (size_t)face * 96 + ch) = o;
}

// ---------------- dense rgb: rgb3[f] = h[f] . Wrgb^T (no bias/clamp yet) ----------------
__global__ void k_rgbdense(const float* __restrict__ h, const float* __restrict__ wrgbmod,
                           f32x4* __restrict__ rgb3)
{
    __shared__ float wsm[288];
    int t = threadIdx.x;
    if (t < 256) wsm[t] = wrgbmod[t];
    if (t < 32)  wsm[256 + t] = wrgbmod[256 + t];   // block=256: must stage all 288 (R4 bug: last 32 were garbage)
    __syncthreads();
    int f = blockIdx.x * 256 + t;
    const float* hr = h + (size_t)f * 96;
    float y0 = 0.f, y1 = 0.f, y2 = 0.f;
    #pragma unroll
    for (int i4 = 0; i4 < 24; ++i4) {
        f32x4 xv = *(const f32x4*)(hr + i4 * 4);
        const float* w0 = wsm + i4 * 4;
        const float* w1 = wsm + 96 + i4 * 4;
        const float* w2 = wsm + 192 + i4 * 4;
        y0 += xv.x * w0[0] + xv.y * w0[1] + xv.z * w0[2] + xv.w * w0[3];
        y1 += xv.x * w1[0] + xv.y * w1[1] + xv.z * w1[2] + xv.w * w1[3];
        y2 += xv.x * w2[0] + xv.y * w2[1] + xv.z * w2[2] + xv.w * w2[3];
    }
    f32x4 o; o.x = y0; o.y = y1; o.z = y2; o.w = 0.f;
    rgb3[f] = o;
}

// ---------------- torgb final: img_out = mean9(img[cidx]) + clamp(rgb3[g0]+b) ----------------
__global__ void k_torgb2(const f32x4* __restrict__ rgb3, const int* __restrict__ fn1,
                         const int* __restrict__ cidx, const float* __restrict__ img,
                         const float* __restrict__ brgb, float* __restrict__ imgout)
{
    int f = blockIdx.x * 256 + threadIdx.x;
    int g0 = fn1[(size_t)f * 9];
    float y0 = 0.f, y1 = 0.f, y2 = 0.f;
    if ((unsigned)g0 < FF) {
        f32x4 y = rgb3[g0];
        y0 = y.x; y1 = y.y; y2 = y.z;
    }
    y0 = fminf(fmaxf(y0 + brgb[0], -CLAMP_V), CLAMP_V);
    y1 = fminf(fmaxf(y1 + brgb[1], -CLAMP_V), CLAMP_V);
    y2 = fminf(fmaxf(y2 + brgb[2], -CLAMP_V), CLAMP_V);
    float i0 = 0.f, i1 = 0.f, i2 = 0.f;
    #pragma unroll
    for (int j = 0; j < 9; ++j) {
        int id = cidx[f * 9 + j];
        if (id >= 0) {
            const float* ir = img + (size_t)id * 3;
            i0 += ir[0]; i1 += ir[1]; i2 += ir[2];
        }
    }
    const float inv9 = 1.f / 9.f;
    imgout[(size_t)f * 3 + 0] = i0 * inv9 + y0;
    imgout[(size_t)f * 3 + 1] = i1 * inv9 + y1;
    imgout[(size_t)f * 3 + 2] = i2 * inv9 + y2;
}

extern "C" void kernel_launch(void* const* d_in, const int* in_sizes, int n_in,
                              void* d_out, int out_size, void* d_ws, size_t ws_size,
                              hipStream_t stream) {
    const float* x     = (const float*)d_in[0];
    const float* sfeat = (const float*)d_in[1];
    const float* img   = (const float*)d_in[2];
    const float* wsv   = (const float*)d_in[3];
    const int* fn0     = (const int*)d_in[4];
    const int* fn1     = (const int*)d_in[5];
    const int* pmap    = (const int*)d_in[6];
    const float* a0w   = (const float*)d_in[9];
    const float* a0b   = (const float*)d_in[10];
    const float* wc0   = (const float*)d_in[11];
    const float* wsd0  = (const float*)d_in[12];
    const float* wcr0  = (const float*)d_in[13];
    const float* ns0   = (const float*)d_in[14];
    const float* bias0 = (const float*)d_in[15];
    const float* nco0  = (const float*)d_in[16];
    const float* a1w   = (const float*)d_in[17];
    const float* a1b   = (const float*)d_in[18];
    const float* wc1   = (const float*)d_in[19];
    const float* wsd1  = (const float*)d_in[20];
    const float* wcr1  = (const float*)d_in[21];
    const float* ns1   = (const float*)d_in[22];
    const float* bias1 = (const float*)d_in[23];
    const float* nco1  = (const float*)d_in[24];
    const float* a2w   = (const float*)d_in[25];
    const float* a2b   = (const float*)d_in[26];
    const float* wrgb  = (const float*)d_in[27];
    const float* brgb  = (const float*)d_in[28];

    char* wsb = (char*)d_ws;
    // small region [0, 262144)
    float* s0            = (float*)(wsb + 0);
    float* s1            = (float*)(wsb + 512);
    float* s2            = (float*)(wsb + 1024);
    float* wrgbmod       = (float*)(wsb + 1536);          // 1152 B
    unsigned* zrow       = (unsigned*)(wsb + 4096);       // 256 B
    unsigned short* wm0  = (unsigned short*)(wsb + 8192); // 98304 B
    unsigned short* wm1  = (unsigned short*)(wsb + 8192 + 98304);  // 73728 B
    // h1 [262144, +33554432)
    unsigned short* h1   = (unsigned short*)(wsb + 262144);
    // cidx [+33554432, +4718592)
    int* cidx            = (int*)(wsb + 262144 + 33554432);
    // big region [38535168, +37748736) — phased reuse, total ws = 76283904 (proven in R3)
    char* big            = wsb + 262144 + 33554432 + 4718592;
    unsigned short* xcat = (unsigned short*)(big);                 // phase 1: 8.39 MB
    unsigned* y0         = (unsigned*)(big + 8388608);             // phase 1: 25.17 MB
    unsigned* hc0        = (unsigned*)(big);                       // phase 2: 8.39 MB (over xcat, xcat dead)
    unsigned* yh         = (unsigned*)(big);                       // phase 3: 37.75 MB (all dead)
    f32x4* rgb3          = (f32x4*)(big);                          // phase 4: 2.10 MB (yh dead)

    float* out_h   = (float*)d_out;
    float* out_img = out_h + (size_t)FF * 96;

    k_misc<<<FC * 32 / 256 + FF * 9 / 256, 256, 0, stream>>>(x, sfeat, (u16x4*)xcat, fn1, pmap, cidx);
    k_prep<<<1, 512, 0, stream>>>(wsv, a0w, a0b, a1w, a1b, a2w, a2b, s0, s1, s2, zrow);
    k_modw<<<128, 128, 0, stream>>>(wc0, wsd0, wcr0, s0, wm0, 128);
    k_modw<<<96, 128, 0, stream>>>(wc1, wsd1, wcr1, s1, wm1, 96);
    k_rgbw<<<1, 320, 0, stream>>>(wrgb, s2, wrgbmod);
    k_gemm0<<<FC / 128, 256, 0, stream>>>(xcat, wm0, y0);
    k_gather0<<<FC * 64 / 256, 256, 0, stream>>>(y0, fn0, zrow, hc0);
    k_upsample<<<FF / 4, 256, 0, stream>>>(hc0, cidx, nco0, ns0, bias0, (unsigned*)h1, zrow);
    k_gemm1h<<<FF / 128, 256, 0, stream>>>(h1, wm1, yh, 0);
    k_gather1h<<<FF * 24 / 256, 256, 0, stream>>>(yh, fn1, zrow, nco1, ns1, bias1, out_h, 0);
    k_gemm1h<<<FF / 128, 256, 0, stream>>>(h1, wm1, yh, 1);
    k_gather1h<<<FF * 24 / 256, 256, 0, stream>>>(yh, fn1, zrow, nco1, ns1, bias1, out_h, 1);
    k_rgbdense<<<FF / 256, 256, 0, stream>>>(out_h, wrgbmod, rgb3);
    k_torgb2<<<FF / 256, 256, 0, stream>>>(rgb3, fn1, cidx, img, brgb, out_img);
}

// Round 6
// 314.598 us; speedup vs baseline: 1.8265x; 1.1860x over previous
//
#include <hip/hip_runtime.h>

#define FC 32768
#define FF 131072
#define LRELU_SLOPE 0.2f
#define ACT_GAIN 1.4142135623730951f
#define CLAMP_V 256.0f

typedef __bf16 bf16x8 __attribute__((ext_vector_type(8)));
typedef float f32x4 __attribute__((ext_vector_type(4)));
typedef float f32x2 __attribute__((ext_vector_type(2)));
typedef unsigned u32x4 __attribute__((ext_vector_type(4)));
typedef unsigned short u16x4 __attribute__((ext_vector_type(4)));

static __device__ __forceinline__ unsigned short f2bf(float f) {
    unsigned u = __float_as_uint(f);
    u += 0x7FFFu + ((u >> 16) & 1u);
    return (unsigned short)(u >> 16);
}
static __device__ __forceinline__ float bf2f(unsigned short u) {
    return __uint_as_float(((unsigned)u) << 16);
}
static __device__ __forceinline__ float actf(float v) {
    v = (v < 0.f) ? v * LRELU_SLOPE : v;
    v *= ACT_GAIN;
    return fminf(fmaxf(v, -CLAMP_V), CLAMP_V);
}

// ---------------- styles: wave-per-output affine + zrow init ----------------
// grid 89 x 256: waves 0..351 = outputs, wave 352 = zrow
__global__ void k_prep2(const float* __restrict__ wsvec,
                        const float* __restrict__ a0w, const float* __restrict__ a0b,
                        const float* __restrict__ a1w, const float* __restrict__ a1b,
                        const float* __restrict__ a2w, const float* __restrict__ a2b,
                        float* __restrict__ s0, float* __restrict__ s1, float* __restrict__ s2,
                        unsigned* __restrict__ zrow)
{
    int lane = threadIdx.x & 63;
    int t = blockIdx.x * 4 + (threadIdx.x >> 6);
    if (t >= 352) {
        if (t == 352) zrow[lane] = 0u;
        return;
    }
    int level, o;
    const float *W, *bptr; float* out;
    if (t < 128)       { level = 0; o = t;       W = a0w; bptr = a0b; out = s0; }
    else if (t < 256)  { level = 1; o = t - 128; W = a1w; bptr = a1b; out = s1; }
    else               { level = 2; o = t - 256; W = a2w; bptr = a2b; out = s2; }
    const float* wrow = wsvec + level * 512;
    const float* Wr = W + (size_t)o * 512;
    f32x4 wa = *(const f32x4*)(wrow + lane * 8);
    f32x4 wb = *(const f32x4*)(wrow + lane * 8 + 4);
    f32x4 va = *(const f32x4*)(Wr + lane * 8);
    f32x4 vb = *(const f32x4*)(Wr + lane * 8 + 4);
    float acc = wa.x * va.x + wa.y * va.y + wa.z * va.z + wa.w * va.w
              + wb.x * vb.x + wb.y * vb.y + wb.z * vb.z + wb.w * vb.w;
    #pragma unroll
    for (int off = 32; off; off >>= 1) acc += __shfl_down(acc, off, 64);
    if (lane == 0) {
        float v = acc * 0.04419417382415922f + bptr[o];
        if (level == 2) v *= 0.10206207261596577f;  // 1/sqrt(96) torgb weight gain
        out[o] = v;
    }
}

// ---------------- fused: cvt (concat->bf16) + composed index ----------------
__global__ void k_misc(const float* __restrict__ x, const float* __restrict__ sf,
                       u16x4* __restrict__ xcat,
                       const int* __restrict__ fn1, const int* __restrict__ pmap,
                       int* __restrict__ cidx)
{
    int b = blockIdx.x;
    if (b < FC * 32 / 256) {
        int gid = b * 256 + threadIdx.x;
        int f = gid >> 5;
        int c4 = (gid & 31) * 4;
        f32x4 v;
        if (c4 < 96) v = *(const f32x4*)(x + (size_t)f * 96 + c4);
        else         v = *(const f32x4*)(sf + (size_t)f * 32 + (c4 - 96));
        u16x4 o;
        o.x = f2bf(v.x); o.y = f2bf(v.y); o.z = f2bf(v.z); o.w = f2bf(v.w);
        xcat[gid] = o;
    } else {
        int gid = (b - FC * 32 / 256) * 256 + threadIdx.x;  // FF*9
        int g = fn1[gid];
        cidx[gid] = ((unsigned)g < FF) ? pmap[g] : -1;
    }
}

// ---------------- fused weight prep: modw0 (blocks 0..127), modw1 (128..223), rgbw (224) ----------------
__global__ void k_wmod(const float* __restrict__ wc0, const float* __restrict__ wsd0,
                       const float* __restrict__ wcr0, const float* __restrict__ s0,
                       unsigned short* __restrict__ wm0,
                       const float* __restrict__ wc1, const float* __restrict__ wsd1,
                       const float* __restrict__ wcr1, const float* __restrict__ s1,
                       unsigned short* __restrict__ wm1,
                       const float* __restrict__ wrgb, const float* __restrict__ s2,
                       float* __restrict__ wrgbmod)
{
    int b = blockIdx.x;
    int i = threadIdx.x;  // 128
    if (b == 224) {
        for (int t = i; t < 288; t += 128) {
            int c = t / 96, k = t % 96;
            wrgbmod[c * 96 + k] = wrgb[c * 96 + k] * s2[k];
        }
        return;
    }
    const float *wc, *wsd, *wcr, *s; unsigned short* out; int o, O;
    if (b < 128) { wc = wc0; wsd = wsd0; wcr = wcr0; s = s0; out = wm0; o = b; O = 128; }
    else         { wc = wc1; wsd = wsd1; wcr = wcr1; s = s1; out = wm1; o = b - 128; O = 96; }
    float sv = s[i];
    float pc = wc[o * 128 + i] * sv;
    float ps = wsd[o * 128 + i] * sv;
    float pr = wcr[o * 128 + i] * sv;
    float part = pc * pc + 4.f * ps * ps + 4.f * pr * pr;
    __shared__ float red[2];
    #pragma unroll
    for (int off = 32; off; off >>= 1) part += __shfl_down(part, off, 64);
    if ((threadIdx.x & 63) == 0) red[threadIdx.x >> 6] = part;
    __syncthreads();
    float d = rsqrtf(red[0] + red[1] + 1e-8f);
    out[(0 * O + o) * 128 + i] = f2bf(pc * d);
    out[(1 * O + o) * 128 + i] = f2bf(ps * d);
    out[(2 * O + o) * 128 + i] = f2bf(pr * d);
}

// ---------------- gemm0: y0_t = xcat . W0_t^T  -> bf16 y0[3][FC][128] ----------------
__launch_bounds__(256, 2)
__global__ void k_gemm0(const unsigned short* __restrict__ xcat, const unsigned short* __restrict__ wm,
                        unsigned* __restrict__ y0)
{
    __shared__ unsigned short sm[4][32 * 136];
    int lane = threadIdx.x & 63;
    int w = threadIdx.x >> 6;
    int fbase = (blockIdx.x * 4 + w) * 32;
    int quad = lane >> 4, l15 = lane & 15;
    const char* hb = (const char*)xcat;
    const char* wb = (const char*)wm;
    unsigned short* lds = sm[w];

    bf16x8 a[2][4];
    #pragma unroll
    for (int mt = 0; mt < 2; ++mt)
        #pragma unroll
        for (int s = 0; s < 4; ++s)
            a[mt][s] = *(const bf16x8*)(hb + (size_t)(fbase + mt * 16 + l15) * 256 + s * 64 + quad * 16);

    for (int t = 0; t < 3; ++t) {
        bf16x8 b[8][4];
        #pragma unroll
        for (int ot = 0; ot < 8; ++ot)
            #pragma unroll
            for (int s = 0; s < 4; ++s)
                b[ot][s] = *(const bf16x8*)(wb + (size_t)(((t * 128 + ot * 16 + l15) * 128 + s * 32 + quad * 8) * 2));
        f32x4 acc[2][8];
        #pragma unroll
        for (int mt = 0; mt < 2; ++mt)
            #pragma unroll
            for (int ot = 0; ot < 8; ++ot)
                #pragma unroll
                for (int r = 0; r < 4; ++r) acc[mt][ot][r] = 0.f;
        #pragma unroll
        for (int s = 0; s < 4; ++s)
            #pragma unroll
            for (int mt = 0; mt < 2; ++mt)
                #pragma unroll
                for (int ot = 0; ot < 8; ++ot)
                    acc[mt][ot] = __builtin_amdgcn_mfma_f32_16x16x32_bf16(a[mt][s], b[ot][s], acc[mt][ot], 0, 0, 0);
        #pragma unroll
        for (int mt = 0; mt < 2; ++mt)
            #pragma unroll
            for (int ot = 0; ot < 8; ++ot)
                #pragma unroll
                for (int r = 0; r < 4; ++r)
                    lds[(mt * 16 + quad * 4 + r) * 136 + ot * 16 + l15] = f2bf(acc[mt][ot][r]);
        unsigned* yt = y0 + (size_t)t * FC * 64;
        #pragma unroll
        for (int it = 0; it < 8; ++it) {
            int ci = it * 64 + lane;
            int face = ci >> 4;
            int off = ci & 15;
            u32x4 val = *(const u32x4*)(lds + face * 136 + off * 8);
            *(u32x4*)(yt + (size_t)(fbase + face) * 64 + off * 4) = val;
        }
    }
}

// ---------------- gather0 (vectorized): hc0[g] = max_k y0_{t(k)}[fn0[g,k]] ----------------
// 16 lanes per face, u32x4 (16B) per lane
__global__ void k_gather0(const unsigned* __restrict__ y0, const int* __restrict__ fn0,
                          const unsigned* __restrict__ zrow, unsigned* __restrict__ hc0)
{
    int gid = blockIdx.x * 256 + threadIdx.x;  // FC*16
    int g = gid >> 4;
    int c = gid & 15;
    int id[9];
    #pragma unroll
    for (int j = 0; j < 9; ++j) id[j] = fn0[g * 9 + j];
    u32x4 v[9];
    #pragma unroll
    for (int j = 0; j < 9; ++j) {
        int t = (j == 0) ? 0 : (j < 5 ? 1 : 2);
        const unsigned* p = ((unsigned)id[j] < FC) ? (y0 + (size_t)t * FC * 64 + (size_t)id[j] * 64) : zrow;
        v[j] = *(const u32x4*)(p + c * 4);
    }
    u32x4 out;
    #pragma unroll
    for (int k = 0; k < 4; ++k) {
        float m0 = bf2f((unsigned short)v[0][k]);
        float m1 = bf2f((unsigned short)(v[0][k] >> 16));
        #pragma unroll
        for (int j = 1; j < 9; ++j) {
            m0 = fmaxf(m0, bf2f((unsigned short)v[j][k]));
            m1 = fmaxf(m1, bf2f((unsigned short)(v[j][k] >> 16)));
        }
        out[k] = (unsigned)f2bf(m0) | ((unsigned)f2bf(m1) << 16);
    }
    *(u32x4*)(hc0 + (size_t)g * 64 + c * 4) = out;
}

// ---------------- upsample (vectorized) + noise + act -> h1 bf16 [FF][128] ----------------
// 16 lanes per face, u32x4 per lane (8 channels)
__global__ void k_upsample(const unsigned* __restrict__ hc, const int* __restrict__ cidx,
                           const float* __restrict__ nco0,
                           const float* __restrict__ ns0p, const float* __restrict__ bias0,
                           unsigned* __restrict__ h1u, const unsigned* __restrict__ zrow)
{
    int gid = blockIdx.x * 256 + threadIdx.x;  // FF*16
    int f = gid >> 4;
    int c = gid & 15;
    int id[9];
    #pragma unroll
    for (int j = 0; j < 9; ++j) id[j] = cidx[f * 9 + j];
    u32x4 v[9];
    #pragma unroll
    for (int j = 0; j < 9; ++j) {
        const unsigned* p = (id[j] >= 0) ? (hc + (size_t)id[j] * 64) : zrow;
        v[j] = *(const u32x4*)(p + c * 4);
    }
    float nz = nco0[f] * ns0p[0];
    f32x4 b0 = *(const f32x4*)(bias0 + c * 8);
    f32x4 b1 = *(const f32x4*)(bias0 + c * 8 + 4);
    const float inv9 = 1.f / 9.f;
    u32x4 out;
    #pragma unroll
    for (int k = 0; k < 4; ++k) {
        float a0 = 0.f, a1 = 0.f;
        #pragma unroll
        for (int j = 0; j < 9; ++j) {
            a0 += bf2f((unsigned short)v[j][k]);
            a1 += bf2f((unsigned short)(v[j][k] >> 16));
        }
        float bb0 = (k < 2) ? ((k == 0) ? b0.x : b0.z) : ((k == 2) ? b1.x : b1.z);
        float bb1 = (k < 2) ? ((k == 0) ? b0.y : b0.w) : ((k == 2) ? b1.y : b1.w);
        a0 = actf(a0 * inv9 + nz + bb0);
        a1 = actf(a1 * inv9 + nz + bb1);
        out[k] = (unsigned)f2bf(a0) | ((unsigned)f2bf(a1) << 16);
    }
    *(u32x4*)(h1u + (size_t)f * 64 + c * 4) = out;
}

// ---------------- gemm1 (full width): y_t = h1 . W_t^T -> bf16 y[3][FF][96] ----------------
__launch_bounds__(256, 2)
__global__ void k_gemm1(const unsigned short* __restrict__ h1, const unsigned short* __restrict__ wm,
                        unsigned* __restrict__ ybase)
{
    __shared__ unsigned short sm[4][32 * 104];
    int lane = threadIdx.x & 63;
    int w = threadIdx.x >> 6;
    int fbase = (blockIdx.x * 4 + w) * 32;
    int quad = lane >> 4, l15 = lane & 15;
    const char* hb = (const char*)h1;
    const char* wb = (const char*)wm;
    unsigned short* lds = sm[w];

    bf16x8 a[2][4];
    #pragma unroll
    for (int mt = 0; mt < 2; ++mt)
        #pragma unroll
        for (int s = 0; s < 4; ++s)
            a[mt][s] = *(const bf16x8*)(hb + (size_t)(fbase + mt * 16 + l15) * 256 + s * 64 + quad * 16);

    for (int t = 0; t < 3; ++t) {
        bf16x8 b[6][4];
        #pragma unroll
        for (int ot = 0; ot < 6; ++ot)
            #pragma unroll
            for (int s = 0; s < 4; ++s)
                b[ot][s] = *(const bf16x8*)(wb + (size_t)(((t * 96 + ot * 16 + l15) * 128 + s * 32 + quad * 8) * 2));
        f32x4 acc[2][6];
        #pragma unroll
        for (int mt = 0; mt < 2; ++mt)
            #pragma unroll
            for (int ot = 0; ot < 6; ++ot)
                #pragma unroll
                for (int r = 0; r < 4; ++r) acc[mt][ot][r] = 0.f;
        #pragma unroll
        for (int s = 0; s < 4; ++s)
            #pragma unroll
            for (int mt = 0; mt < 2; ++mt)
                #pragma unroll
                for (int ot = 0; ot < 6; ++ot)
                    acc[mt][ot] = __builtin_amdgcn_mfma_f32_16x16x32_bf16(a[mt][s], b[ot][s], acc[mt][ot], 0, 0, 0);
        #pragma unroll
        for (int mt = 0; mt < 2; ++mt)
            #pragma unroll
            for (int ot = 0; ot < 6; ++ot)
                #pragma unroll
                for (int r = 0; r < 4; ++r)
                    lds[(mt * 16 + quad * 4 + r) * 104 + ot * 16 + l15] = f2bf(acc[mt][ot][r]);
        unsigned* yt = ybase + (size_t)t * FF * 48;
        #pragma unroll
        for (int it = 0; it < 6; ++it) {
            int ci = it * 64 + lane;
            int face = ci / 12;
            int off = ci - face * 12;
            u32x4 val = *(const u32x4*)(lds + face * 104 + off * 8);
            *(u32x4*)(yt + (size_t)(fbase + face) * 48 + off * 4) = val;
        }
    }
}

// ---------------- gather1 (vectorized, full width): out_h = act(max_k y + nz + b) ----------------
// 16-lane groups per face; lanes 0..11 each handle 8 channels via u32x4
__global__ void k_gather1(const char* __restrict__ yb, const int* __restrict__ fn1,
                          const unsigned* __restrict__ zrow,
                          const float* __restrict__ nco1, const float* __restrict__ ns1p,
                          const float* __restrict__ bias1, float* __restrict__ hout)
{
    int gid = blockIdx.x * 256 + threadIdx.x;  // FF*16
    int f = gid >> 4;
    int c = gid & 15;
    if (c >= 12) return;
    int id[9];
    #pragma unroll
    for (int j = 0; j < 9; ++j) id[j] = fn1[f * 9 + j];
    u32x4 v[9];
    #pragma unroll
    for (int j = 0; j < 9; ++j) {
        int t = (j == 0) ? 0 : (j < 5 ? 1 : 2);
        const char* p = ((unsigned)id[j] < FF) ? (yb + (size_t)t * FF * 192 + (size_t)id[j] * 192) : (const char*)zrow;
        v[j] = *(const u32x4*)(p + c * 16);
    }
    float nz = nco1[f] * ns1p[0];
    f32x4 o0, o1;
    #pragma unroll
    for (int k = 0; k < 4; ++k) {
        float m0 = bf2f((unsigned short)v[0][k]);
        float m1 = bf2f((unsigned short)(v[0][k] >> 16));
        #pragma unroll
        for (int j = 1; j < 9; ++j) {
            m0 = fmaxf(m0, bf2f((unsigned short)v[j][k]));
            m1 = fmaxf(m1, bf2f((unsigned short)(v[j][k] >> 16)));
        }
        float r0 = actf(m0 + nz + bias1[c * 8 + k * 2]);
        float r1 = actf(m1 + nz + bias1[c * 8 + k * 2 + 1]);
        if (k < 2) { o0[k * 2] = r0; o0[k * 2 + 1] = r1; }
        else       { o1[(k - 2) * 2] = r0; o1[(k - 2) * 2 + 1] = r1; }
    }
    float* op = hout + (size_t)f * 96 + c * 8;
    *(f32x4*)op = o0;
    *(f32x4*)(op + 4) = o1;
}

// ---------------- dense rgb: rgb3[f] = h[f] . Wrgb^T ----------------
__global__ void k_rgbdense(const float* __restrict__ h, const float* __restrict__ wrgbmod,
                           f32x4* __restrict__ rgb3)
{
    __shared__ float wsm[288];
    int t = threadIdx.x;
    if (t < 256) wsm[t] = wrgbmod[t];
    if (t < 32)  wsm[256 + t] = wrgbmod[256 + t];
    __syncthreads();
    int f = blockIdx.x * 256 + t;
    const float* hr = h + (size_t)f * 96;
    float y0 = 0.f, y1 = 0.f, y2 = 0.f;
    #pragma unroll
    for (int i4 = 0; i4 < 24; ++i4) {
        f32x4 xv = *(const f32x4*)(hr + i4 * 4);
        const float* w0 = wsm + i4 * 4;
        const float* w1 = wsm + 96 + i4 * 4;
        const float* w2 = wsm + 192 + i4 * 4;
        y0 += xv.x * w0[0] + xv.y * w0[1] + xv.z * w0[2] + xv.w * w0[3];
        y1 += xv.x * w1[0] + xv.y * w1[1] + xv.z * w1[2] + xv.w * w1[3];
        y2 += xv.x * w2[0] + xv.y * w2[1] + xv.z * w2[2] + xv.w * w2[3];
    }
    f32x4 o; o.x = y0; o.y = y1; o.z = y2; o.w = 0.f;
    rgb3[f] = o;
}

// ---------------- torgb final: img_out = mean9(img[cidx]) + clamp(rgb3[g0]+b) ----------------
__global__ void k_torgb2(const f32x4* __restrict__ rgb3, const int* __restrict__ fn1,
                         const int* __restrict__ cidx, const float* __restrict__ img,
                         const float* __restrict__ brgb, float* __restrict__ imgout)
{
    int f = blockIdx.x * 256 + threadIdx.x;
    int g0 = fn1[(size_t)f * 9];
    float y0 = 0.f, y1 = 0.f, y2 = 0.f;
    if ((unsigned)g0 < FF) {
        f32x4 y = rgb3[g0];
        y0 = y.x; y1 = y.y; y2 = y.z;
    }
    y0 = fminf(fmaxf(y0 + brgb[0], -CLAMP_V), CLAMP_V);
    y1 = fminf(fmaxf(y1 + brgb[1], -CLAMP_V), CLAMP_V);
    y2 = fminf(fmaxf(y2 + brgb[2], -CLAMP_V), CLAMP_V);
    float i0 = 0.f, i1 = 0.f, i2 = 0.f;
    #pragma unroll
    for (int j = 0; j < 9; ++j) {
        int id = cidx[f * 9 + j];
        if (id >= 0) {
            const float* ir = img + (size_t)id * 3;
            i0 += ir[0]; i1 += ir[1]; i2 += ir[2];
        }
    }
    const float inv9 = 1.f / 9.f;
    imgout[(size_t)f * 3 + 0] = i0 * inv9 + y0;
    imgout[(size_t)f * 3 + 1] = i1 * inv9 + y1;
    imgout[(size_t)f * 3 + 2] = i2 * inv9 + y2;
}

extern "C" void kernel_launch(void* const* d_in, const int* in_sizes, int n_in,
                              void* d_out, int out_size, void* d_ws, size_t ws_size,
                              hipStream_t stream) {
    const float* x     = (const float*)d_in[0];
    const float* sfeat = (const float*)d_in[1];
    const float* img   = (const float*)d_in[2];
    const float* wsv   = (const float*)d_in[3];
    const int* fn0     = (const int*)d_in[4];
    const int* fn1     = (const int*)d_in[5];
    const int* pmap    = (const int*)d_in[6];
    const float* a0w   = (const float*)d_in[9];
    const float* a0b   = (const float*)d_in[10];
    const float* wc0   = (const float*)d_in[11];
    const float* wsd0  = (const float*)d_in[12];
    const float* wcr0  = (const float*)d_in[13];
    const float* ns0   = (const float*)d_in[14];
    const float* bias0 = (const float*)d_in[15];
    const float* nco0  = (const float*)d_in[16];
    const float* a1w   = (const float*)d_in[17];
    const float* a1b   = (const float*)d_in[18];
    const float* wc1   = (const float*)d_in[19];
    const float* wsd1  = (const float*)d_in[20];
    const float* wcr1  = (const float*)d_in[21];
    const float* ns1   = (const float*)d_in[22];
    const float* bias1 = (const float*)d_in[23];
    const float* nco1  = (const float*)d_in[24];
    const float* a2w   = (const float*)d_in[25];
    const float* a2b   = (const float*)d_in[26];
    const float* wrgb  = (const float*)d_in[27];
    const float* brgb  = (const float*)d_in[28];

    char* wsb = (char*)d_ws;
    // ws_size = 256 MiB (measured via harness poison fill R5); ~151 MB used, no aliasing
    float* s0            = (float*)(wsb + 0);
    float* s1            = (float*)(wsb + 512);
    float* s2            = (float*)(wsb + 1024);
    float* wrgbmod       = (float*)(wsb + 1536);
    unsigned* zrow       = (unsigned*)(wsb + 4096);
    unsigned short* wm0  = (unsigned short*)(wsb + 8192);
    unsigned short* wm1  = (unsigned short*)(wsb + 8192 + 98304);
    unsigned short* xcat = (unsigned short*)(wsb + 262144);      // 8.39 MB
    unsigned* y0         = (unsigned*)(wsb + 8650752);           // 25.17 MB
    unsigned* hc0        = (unsigned*)(wsb + 33816576);          // 8.39 MB
    unsigned short* h1   = (unsigned short*)(wsb + 42205184);    // 33.55 MB
    int* cidx            = (int*)(wsb + 75759616);               // 4.72 MB
    unsigned* ybase      = (unsigned*)(wsb + 80478208);          // 75.50 MB
    f32x4* rgb3          = (f32x4*)(wsb + 155975680);            // 2.10 MB

    float* out_h   = (float*)d_out;
    float* out_img = out_h + (size_t)FF * 96;

    k_misc<<<FC * 32 / 256 + FF * 9 / 256, 256, 0, stream>>>(x, sfeat, (u16x4*)xcat, fn1, pmap, cidx);
    k_prep2<<<89, 256, 0, stream>>>(wsv, a0w, a0b, a1w, a1b, a2w, a2b, s0, s1, s2, zrow);
    k_wmod<<<225, 128, 0, stream>>>(wc0, wsd0, wcr0, s0, wm0,
                                    wc1, wsd1, wcr1, s1, wm1, wrgb, s2, wrgbmod);
    k_gemm0<<<FC / 128, 256, 0, stream>>>(xcat, wm0, y0);
    k_gather0<<<FC * 16 / 256, 256, 0, stream>>>(y0, fn0, zrow, hc0);
    k_upsample<<<FF * 16 / 256, 256, 0, stream>>>(hc0, cidx, nco0, ns0, bias0, (unsigned*)h1, zrow);
    k_gemm1<<<FF / 128, 256, 0, stream>>>(h1, wm1, ybase);
    k_gather1<<<FF * 16 / 256, 256, 0, stream>>>((const char*)ybase, fn1, zrow, nco1, ns1, bias1, out_h);
    k_rgbdense<<<FF / 256, 256, 0, stream>>>(out_h, wrgbmod, rgb3);
    k_torgb2<<<FF / 256, 256, 0, stream>>>(rgb3, fn1, cidx, img, brgb, out_img);
}

// Round 7
// 312.265 us; speedup vs baseline: 1.8401x; 1.0075x over previous
//
#include <hip/hip_runtime.h>

#define FC 32768
#define FF 131072
#define LRELU_SLOPE 0.2f
#define ACT_GAIN 1.4142135623730951f
#define CLAMP_V 256.0f

typedef __bf16 bf16x8 __attribute__((ext_vector_type(8)));
typedef float f32x4 __attribute__((ext_vector_type(4)));
typedef float f32x2 __attribute__((ext_vector_type(2)));
typedef unsigned u32x4 __attribute__((ext_vector_type(4)));
typedef unsigned u32x2 __attribute__((ext_vector_type(2)));
typedef unsigned short u16x4 __attribute__((ext_vector_type(4)));

static __device__ __forceinline__ unsigned short f2bf(float f) {
    unsigned u = __float_as_uint(f);
    u += 0x7FFFu + ((u >> 16) & 1u);
    return (unsigned short)(u >> 16);
}
static __device__ __forceinline__ unsigned packbf(float a, float b) {
    return (unsigned)f2bf(a) | ((unsigned)f2bf(b) << 16);
}
static __device__ __forceinline__ float bf2f(unsigned short u) {
    return __uint_as_float(((unsigned)u) << 16);
}
static __device__ __forceinline__ float actf(float v) {
    v = (v < 0.f) ? v * LRELU_SLOPE : v;
    v *= ACT_GAIN;
    return fminf(fmaxf(v, -CLAMP_V), CLAMP_V);
}

// ---------------- styles: wave-per-output affine + zrow init ----------------
__global__ void k_prep2(const float* __restrict__ wsvec,
                        const float* __restrict__ a0w, const float* __restrict__ a0b,
                        const float* __restrict__ a1w, const float* __restrict__ a1b,
                        const float* __restrict__ a2w, const float* __restrict__ a2b,
                        float* __restrict__ s0, float* __restrict__ s1, float* __restrict__ s2,
                        unsigned* __restrict__ zrow)
{
    int lane = threadIdx.x & 63;
    int t = blockIdx.x * 4 + (threadIdx.x >> 6);
    if (t >= 352) {
        if (t == 352) zrow[lane] = 0u;
        return;
    }
    int level, o;
    const float *W, *bptr; float* out;
    if (t < 128)       { level = 0; o = t;       W = a0w; bptr = a0b; out = s0; }
    else if (t < 256)  { level = 1; o = t - 128; W = a1w; bptr = a1b; out = s1; }
    else               { level = 2; o = t - 256; W = a2w; bptr = a2b; out = s2; }
    const float* wrow = wsvec + level * 512;
    const float* Wr = W + (size_t)o * 512;
    f32x4 wa = *(const f32x4*)(wrow + lane * 8);
    f32x4 wb = *(const f32x4*)(wrow + lane * 8 + 4);
    f32x4 va = *(const f32x4*)(Wr + lane * 8);
    f32x4 vb = *(const f32x4*)(Wr + lane * 8 + 4);
    float acc = wa.x * va.x + wa.y * va.y + wa.z * va.z + wa.w * va.w
              + wb.x * vb.x + wb.y * vb.y + wb.z * vb.z + wb.w * vb.w;
    #pragma unroll
    for (int off = 32; off; off >>= 1) acc += __shfl_down(acc, off, 64);
    if (lane == 0) {
        float v = acc * 0.04419417382415922f + bptr[o];
        if (level == 2) v *= 0.10206207261596577f;  // 1/sqrt(96) torgb weight gain
        out[o] = v;
    }
}

// ---------------- fused: cvt (concat->bf16) + composed index ----------------
__global__ void k_misc(const float* __restrict__ x, const float* __restrict__ sf,
                       u16x4* __restrict__ xcat,
                       const int* __restrict__ fn1, const int* __restrict__ pmap,
                       int* __restrict__ cidx)
{
    int b = blockIdx.x;
    if (b < FC * 32 / 256) {
        int gid = b * 256 + threadIdx.x;
        int f = gid >> 5;
        int c4 = (gid & 31) * 4;
        f32x4 v;
        if (c4 < 96) v = *(const f32x4*)(x + (size_t)f * 96 + c4);
        else         v = *(const f32x4*)(sf + (size_t)f * 32 + (c4 - 96));
        u16x4 o;
        o.x = f2bf(v.x); o.y = f2bf(v.y); o.z = f2bf(v.z); o.w = f2bf(v.w);
        xcat[gid] = o;
    } else {
        int gid = (b - FC * 32 / 256) * 256 + threadIdx.x;  // FF*9
        int g = fn1[gid];
        cidx[gid] = ((unsigned)g < FF) ? pmap[g] : -1;
    }
}

// ---------------- fused weight prep ----------------
__global__ void k_wmod(const float* __restrict__ wc0, const float* __restrict__ wsd0,
                       const float* __restrict__ wcr0, const float* __restrict__ s0,
                       unsigned short* __restrict__ wm0,
                       const float* __restrict__ wc1, const float* __restrict__ wsd1,
                       const float* __restrict__ wcr1, const float* __restrict__ s1,
                       unsigned short* __restrict__ wm1,
                       const float* __restrict__ wrgb, const float* __restrict__ s2,
                       float* __restrict__ wrgbmod)
{
    int b = blockIdx.x;
    int i = threadIdx.x;  // 128
    if (b == 224) {
        for (int t = i; t < 288; t += 128) {
            int c = t / 96, k = t % 96;
            wrgbmod[c * 96 + k] = wrgb[c * 96 + k] * s2[k];
        }
        return;
    }
    const float *wc, *wsd, *wcr, *s; unsigned short* out; int o, O;
    if (b < 128) { wc = wc0; wsd = wsd0; wcr = wcr0; s = s0; out = wm0; o = b; O = 128; }
    else         { wc = wc1; wsd = wsd1; wcr = wcr1; s = s1; out = wm1; o = b - 128; O = 96; }
    float sv = s[i];
    float pc = wc[o * 128 + i] * sv;
    float ps = wsd[o * 128 + i] * sv;
    float pr = wcr[o * 128 + i] * sv;
    float part = pc * pc + 4.f * ps * ps + 4.f * pr * pr;
    __shared__ float red[2];
    #pragma unroll
    for (int off = 32; off; off >>= 1) part += __shfl_down(part, off, 64);
    if ((threadIdx.x & 63) == 0) red[threadIdx.x >> 6] = part;
    __syncthreads();
    float d = rsqrtf(red[0] + red[1] + 1e-8f);
    out[(0 * O + o) * 128 + i] = f2bf(pc * d);
    out[(1 * O + o) * 128 + i] = f2bf(ps * d);
    out[(2 * O + o) * 128 + i] = f2bf(pr * d);
}

// ---------------- gemm0 (swapped operands, t-split, no LDS) ----------------
// grid 768: t = bx%3, chunk = bx/3. C row=channel, col=face -> 8B packed stores.
__launch_bounds__(256, 3)
__global__ void k_gemm0(const unsigned short* __restrict__ xcat, const unsigned short* __restrict__ wm,
                        unsigned* __restrict__ y0)
{
    int lane = threadIdx.x & 63;
    int w = threadIdx.x >> 6;
    int bx = blockIdx.x;
    int t = bx % 3, chunk = bx / 3;
    int fbase = (chunk * 4 + w) * 32;
    int quad = lane >> 4, l15 = lane & 15;
    const char* hb = (const char*)xcat;
    const char* wb = (const char*)wm;

    bf16x8 bfr[2][4];
    #pragma unroll
    for (int nt = 0; nt < 2; ++nt)
        #pragma unroll
        for (int s = 0; s < 4; ++s)
            bfr[nt][s] = *(const bf16x8*)(hb + (size_t)(fbase + nt * 16 + l15) * 256 + s * 64 + quad * 16);

    f32x4 acc[2][8];
    #pragma unroll
    for (int nt = 0; nt < 2; ++nt)
        #pragma unroll
        for (int mt = 0; mt < 8; ++mt)
            #pragma unroll
            for (int r = 0; r < 4; ++r) acc[nt][mt][r] = 0.f;

    #pragma unroll
    for (int s = 0; s < 4; ++s) {
        bf16x8 afr[8];
        #pragma unroll
        for (int mt = 0; mt < 8; ++mt)
            afr[mt] = *(const bf16x8*)(wb + (size_t)(((t * 128 + mt * 16 + l15) * 128 + s * 32 + quad * 8) * 2));
        #pragma unroll
        for (int nt = 0; nt < 2; ++nt)
            #pragma unroll
            for (int mt = 0; mt < 8; ++mt)
                acc[nt][mt] = __builtin_amdgcn_mfma_f32_16x16x32_bf16(afr[mt], bfr[nt][s], acc[nt][mt], 0, 0, 0);
    }

    unsigned* yt = y0 + (size_t)t * FC * 64;
    #pragma unroll
    for (int nt = 0; nt < 2; ++nt) {
        int face = fbase + nt * 16 + l15;
        #pragma unroll
        for (int mt = 0; mt < 8; ++mt) {
            u32x2 v;
            v.x = packbf(acc[nt][mt][0], acc[nt][mt][1]);
            v.y = packbf(acc[nt][mt][2], acc[nt][mt][3]);
            *(u32x2*)(yt + (size_t)face * 64 + mt * 8 + quad * 2) = v;
        }
    }
}

// ---------------- gather0: hc0[g] = max_k y0_{t(k)}[fn0[g,k]] ----------------
__global__ void k_gather0(const unsigned* __restrict__ y0, const int* __restrict__ fn0,
                          const unsigned* __restrict__ zrow, unsigned* __restrict__ hc0)
{
    int gid = blockIdx.x * 256 + threadIdx.x;  // FC*16
    int g = gid >> 4;
    int c = gid & 15;
    int id[9];
    #pragma unroll
    for (int j = 0; j < 9; ++j) id[j] = fn0[g * 9 + j];
    u32x4 v[9];
    #pragma unroll
    for (int j = 0; j < 9; ++j) {
        int t = (j == 0) ? 0 : (j < 5 ? 1 : 2);
        const unsigned* p = ((unsigned)id[j] < FC) ? (y0 + (size_t)t * FC * 64 + (size_t)id[j] * 64) : zrow;
        v[j] = *(const u32x4*)(p + c * 4);
    }
    u32x4 out;
    #pragma unroll
    for (int k = 0; k < 4; ++k) {
        float m0 = bf2f((unsigned short)v[0][k]);
        float m1 = bf2f((unsigned short)(v[0][k] >> 16));
        #pragma unroll
        for (int j = 1; j < 9; ++j) {
            m0 = fmaxf(m0, bf2f((unsigned short)v[j][k]));
            m1 = fmaxf(m1, bf2f((unsigned short)(v[j][k] >> 16)));
        }
        out[k] = packbf(m0, m1);
    }
    *(u32x4*)(hc0 + (size_t)g * 64 + c * 4) = out;
}

// ---------------- upsample + noise + act -> h1 bf16 [FF][128] ----------------
__global__ void k_upsample(const unsigned* __restrict__ hc, const int* __restrict__ cidx,
                           const float* __restrict__ nco0,
                           const float* __restrict__ ns0p, const float* __restrict__ bias0,
                           unsigned* __restrict__ h1u, const unsigned* __restrict__ zrow)
{
    int gid = blockIdx.x * 256 + threadIdx.x;  // FF*16
    int f = gid >> 4;
    int c = gid & 15;
    int id[9];
    #pragma unroll
    for (int j = 0; j < 9; ++j) id[j] = cidx[f * 9 + j];
    u32x4 v[9];
    #pragma unroll
    for (int j = 0; j < 9; ++j) {
        const unsigned* p = (id[j] >= 0) ? (hc + (size_t)id[j] * 64) : zrow;
        v[j] = *(const u32x4*)(p + c * 4);
    }
    float nz = nco0[f] * ns0p[0];
    f32x4 b0 = *(const f32x4*)(bias0 + c * 8);
    f32x4 b1 = *(const f32x4*)(bias0 + c * 8 + 4);
    const float inv9 = 1.f / 9.f;
    u32x4 out;
    #pragma unroll
    for (int k = 0; k < 4; ++k) {
        float a0 = 0.f, a1 = 0.f;
        #pragma unroll
        for (int j = 0; j < 9; ++j) {
            a0 += bf2f((unsigned short)v[j][k]);
            a1 += bf2f((unsigned short)(v[j][k] >> 16));
        }
        float bb0 = (k < 2) ? ((k == 0) ? b0.x : b0.z) : ((k == 2) ? b1.x : b1.z);
        float bb1 = (k < 2) ? ((k == 0) ? b0.y : b0.w) : ((k == 2) ? b1.y : b1.w);
        a0 = actf(a0 * inv9 + nz + bb0);
        a1 = actf(a1 * inv9 + nz + bb1);
        out[k] = packbf(a0, a1);
    }
    *(u32x4*)(h1u + (size_t)f * 64 + c * 4) = out;
}

// ---------------- gemm1 (swapped operands, t-split, no LDS) ----------------
// grid 3072: t = bx%3, chunk = bx/3.
__launch_bounds__(256, 4)
__global__ void k_gemm1(const unsigned short* __restrict__ h1, const unsigned short* __restrict__ wm,
                        unsigned* __restrict__ ybase)
{
    int lane = threadIdx.x & 63;
    int w = threadIdx.x >> 6;
    int bx = blockIdx.x;
    int t = bx % 3, chunk = bx / 3;
    int fbase = (chunk * 4 + w) * 32;
    int quad = lane >> 4, l15 = lane & 15;
    const char* hb = (const char*)h1;
    const char* wb = (const char*)wm;

    bf16x8 bfr[2][4];
    #pragma unroll
    for (int nt = 0; nt < 2; ++nt)
        #pragma unroll
        for (int s = 0; s < 4; ++s)
            bfr[nt][s] = *(const bf16x8*)(hb + (size_t)(fbase + nt * 16 + l15) * 256 + s * 64 + quad * 16);

    f32x4 acc[2][6];
    #pragma unroll
    for (int nt = 0; nt < 2; ++nt)
        #pragma unroll
        for (int mt = 0; mt < 6; ++mt)
            #pragma unroll
            for (int r = 0; r < 4; ++r) acc[nt][mt][r] = 0.f;

    #pragma unroll
    for (int s = 0; s < 4; ++s) {
        bf16x8 afr[6];
        #pragma unroll
        for (int mt = 0; mt < 6; ++mt)
            afr[mt] = *(const bf16x8*)(wb + (size_t)(((t * 96 + mt * 16 + l15) * 128 + s * 32 + quad * 8) * 2));
        #pragma unroll
        for (int nt = 0; nt < 2; ++nt)
            #pragma unroll
            for (int mt = 0; mt < 6; ++mt)
                acc[nt][mt] = __builtin_amdgcn_mfma_f32_16x16x32_bf16(afr[mt], bfr[nt][s], acc[nt][mt], 0, 0, 0);
    }

    unsigned* yt = ybase + (size_t)t * FF * 48;
    #pragma unroll
    for (int nt = 0; nt < 2; ++nt) {
        int face = fbase + nt * 16 + l15;
        #pragma unroll
        for (int mt = 0; mt < 6; ++mt) {
            u32x2 v;
            v.x = packbf(acc[nt][mt][0], acc[nt][mt][1]);
            v.y = packbf(acc[nt][mt][2], acc[nt][mt][3]);
            *(u32x2*)(yt + (size_t)face * 48 + mt * 8 + quad * 2) = v;
        }
    }
}

// ---------------- gather1 + fused rgb dot: out_h + rgb3 ----------------
// 16 lanes per face; lanes 0..11 hold 8 channels each (full 96-ch row in-register)
__global__ void k_gather1(const char* __restrict__ yb, const int* __restrict__ fn1,
                          const unsigned* __restrict__ zrow,
                          const float* __restrict__ nco1, const float* __restrict__ ns1p,
                          const float* __restrict__ bias1, const float* __restrict__ wrgbmod,
                          float* __restrict__ hout, f32x4* __restrict__ rgb3)
{
    int gid = blockIdx.x * 256 + threadIdx.x;  // FF*16
    int f = gid >> 4;
    int c = gid & 15;
    int ce = (c < 12) ? c : 11;   // lanes 12..15 compute dummy (zero-masked) work
    int id[9];
    #pragma unroll
    for (int j = 0; j < 9; ++j) id[j] = fn1[f * 9 + j];
    u32x4 v[9];
    #pragma unroll
    for (int j = 0; j < 9; ++j) {
        int t = (j == 0) ? 0 : (j < 5 ? 1 : 2);
        const char* p = ((unsigned)id[j] < FF) ? (yb + (size_t)t * FF * 192 + (size_t)id[j] * 192) : (const char*)zrow;
        v[j] = *(const u32x4*)(p + ce * 16);
    }
    float nz = nco1[f] * ns1p[0];
    f32x4 o0, o1;
    #pragma unroll
    for (int k = 0; k < 4; ++k) {
        float m0 = bf2f((unsigned short)v[0][k]);
        float m1 = bf2f((unsigned short)(v[0][k] >> 16));
        #pragma unroll
        for (int j = 1; j < 9; ++j) {
            m0 = fmaxf(m0, bf2f((unsigned short)v[j][k]));
            m1 = fmaxf(m1, bf2f((unsigned short)(v[j][k] >> 16)));
        }
        float r0 = actf(m0 + nz + bias1[ce * 8 + k * 2]);
        float r1 = actf(m1 + nz + bias1[ce * 8 + k * 2 + 1]);
        if (k < 2) { o0[k * 2] = r0; o0[k * 2 + 1] = r1; }
        else       { o1[(k - 2) * 2] = r0; o1[(k - 2) * 2 + 1] = r1; }
    }
    // fused rgb partial dot (mask out duplicate lanes 12..15)
    float msk = (c < 12) ? 1.f : 0.f;
    f32x4 w00 = *(const f32x4*)(wrgbmod + ce * 8);
    f32x4 w01 = *(const f32x4*)(wrgbmod + ce * 8 + 4);
    f32x4 w10 = *(const f32x4*)(wrgbmod + 96 + ce * 8);
    f32x4 w11 = *(const f32x4*)(wrgbmod + 96 + ce * 8 + 4);
    f32x4 w20 = *(const f32x4*)(wrgbmod + 192 + ce * 8);
    f32x4 w21 = *(const f32x4*)(wrgbmod + 192 + ce * 8 + 4);
    float p0 = msk * (o0.x * w00.x + o0.y * w00.y + o0.z * w00.z + o0.w * w00.w
                    + o1.x * w01.x + o1.y * w01.y + o1.z * w01.z + o1.w * w01.w);
    float p1 = msk * (o0.x * w10.x + o0.y * w10.y + o0.z * w10.z + o0.w * w10.w
                    + o1.x * w11.x + o1.y * w11.y + o1.z * w11.z + o1.w * w11.w);
    float p2 = msk * (o0.x * w20.x + o0.y * w20.y + o0.z * w20.z + o0.w * w20.w
                    + o1.x * w21.x + o1.y * w21.y + o1.z * w21.z + o1.w * w21.w);
    #pragma unroll
    for (int off = 8; off; off >>= 1) {
        p0 += __shfl_xor(p0, off, 16);
        p1 += __shfl_xor(p1, off, 16);
        p2 += __shfl_xor(p2, off, 16);
    }
    if (c < 12) {
        float* op = hout + (size_t)f * 96 + c * 8;
        *(f32x4*)op = o0;
        *(f32x4*)(op + 4) = o1;
    }
    if (c == 12) {
        f32x4 o; o.x = p0; o.y = p1; o.z = p2; o.w = 0.f;
        rgb3[f] = o;
    }
}

// ---------------- torgb final: img_out = mean9(img[cidx]) + clamp(rgb3[g0]+b) ----------------
__global__ void k_torgb2(const f32x4* __restrict__ rgb3, const int* __restrict__ fn1,
                         const int* __restrict__ cidx, const float* __restrict__ img,
                         const float* __restrict__ brgb, float* __restrict__ imgout)
{
    int f = blockIdx.x * 256 + threadIdx.x;
    int g0 = fn1[(size_t)f * 9];
    float y0 = 0.f, y1 = 0.f, y2 = 0.f;
    if ((unsigned)g0 < FF) {
        f32x4 y = rgb3[g0];
        y0 = y.x; y1 = y.y; y2 = y.z;
    }
    y0 = fminf(fmaxf(y0 + brgb[0], -CLAMP_V), CLAMP_V);
    y1 = fminf(fmaxf(y1 + brgb[1], -CLAMP_V), CLAMP_V);
    y2 = fminf(fmaxf(y2 + brgb[2], -CLAMP_V), CLAMP_V);
    float i0 = 0.f, i1 = 0.f, i2 = 0.f;
    #pragma unroll
    for (int j = 0; j < 9; ++j) {
        int id = cidx[f * 9 + j];
        if (id >= 0) {
            const float* ir = img + (size_t)id * 3;
            i0 += ir[0]; i1 += ir[1]; i2 += ir[2];
        }
    }
    const float inv9 = 1.f / 9.f;
    imgout[(size_t)f * 3 + 0] = i0 * inv9 + y0;
    imgout[(size_t)f * 3 + 1] = i1 * inv9 + y1;
    imgout[(size_t)f * 3 + 2] = i2 * inv9 + y2;
}

extern "C" void kernel_launch(void* const* d_in, const int* in_sizes, int n_in,
                              void* d_out, int out_size, void* d_ws, size_t ws_size,
                              hipStream_t stream) {
    const float* x     = (const float*)d_in[0];
    const float* sfeat = (const float*)d_in[1];
    const float* img   = (const float*)d_in[2];
    const float* wsv   = (const float*)d_in[3];
    const int* fn0     = (const int*)d_in[4];
    const int* fn1     = (const int*)d_in[5];
    const int* pmap    = (const int*)d_in[6];
    const float* a0w   = (const float*)d_in[9];
    const float* a0b   = (const float*)d_in[10];
    const float* wc0   = (const float*)d_in[11];
    const float* wsd0  = (const float*)d_in[12];
    const float* wcr0  = (const float*)d_in[13];
    const float* ns0   = (const float*)d_in[14];
    const float* bias0 = (const float*)d_in[15];
    const float* nco0  = (const float*)d_in[16];
    const float* a1w   = (const float*)d_in[17];
    const float* a1b   = (const float*)d_in[18];
    const float* wc1   = (const float*)d_in[19];
    const float* wsd1  = (const float*)d_in[20];
    const float* wcr1  = (const float*)d_in[21];
    const float* ns1   = (const float*)d_in[22];
    const float* bias1 = (const float*)d_in[23];
    const float* nco1  = (const float*)d_in[24];
    const float* a2w   = (const float*)d_in[25];
    const float* a2b   = (const float*)d_in[26];
    const float* wrgb  = (const float*)d_in[27];
    const float* brgb  = (const float*)d_in[28];

    char* wsb = (char*)d_ws;
    float* s0            = (float*)(wsb + 0);
    float* s1            = (float*)(wsb + 512);
    float* s2            = (float*)(wsb + 1024);
    float* wrgbmod       = (float*)(wsb + 1536);
    unsigned* zrow       = (unsigned*)(wsb + 4096);
    unsigned short* wm0  = (unsigned short*)(wsb + 8192);
    unsigned short* wm1  = (unsigned short*)(wsb + 8192 + 98304);
    unsigned short* xcat = (unsigned short*)(wsb + 262144);      // 8.39 MB
    unsigned* y0         = (unsigned*)(wsb + 8650752);           // 25.17 MB
    unsigned* hc0        = (unsigned*)(wsb + 33816576);          // 8.39 MB
    unsigned short* h1   = (unsigned short*)(wsb + 42205184);    // 33.55 MB
    int* cidx            = (int*)(wsb + 75759616);               // 4.72 MB
    unsigned* ybase      = (unsigned*)(wsb + 80478208);          // 75.50 MB
    f32x4* rgb3          = (f32x4*)(wsb + 155975680);            // 2.10 MB

    float* out_h   = (float*)d_out;
    float* out_img = out_h + (size_t)FF * 96;

    k_misc<<<FC * 32 / 256 + FF * 9 / 256, 256, 0, stream>>>(x, sfeat, (u16x4*)xcat, fn1, pmap, cidx);
    k_prep2<<<89, 256, 0, stream>>>(wsv, a0w, a0b, a1w, a1b, a2w, a2b, s0, s1, s2, zrow);
    k_wmod<<<225, 128, 0, stream>>>(wc0, wsd0, wcr0, s0, wm0,
                                    wc1, wsd1, wcr1, s1, wm1, wrgb, s2, wrgbmod);
    k_gemm0<<<768, 256, 0, stream>>>(xcat, wm0, y0);
    k_gather0<<<FC * 16 / 256, 256, 0, stream>>>(y0, fn0, zrow, hc0);
    k_upsample<<<FF * 16 / 256, 256, 0, stream>>>(hc0, cidx, nco0, ns0, bias0, (unsigned*)h1, zrow);
    k_gemm1<<<3072, 256, 0, stream>>>(h1, wm1, ybase);
    k_gather1<<<FF * 16 / 256, 256, 0, stream>>>((const char*)ybase, fn1, zrow, nco1, ns1, bias1,
                                                 wrgbmod, out_h, rgb3);
    k_torgb2<<<FF / 256, 256, 0, stream>>>(rgb3, fn1, cidx, img, brgb, out_img);
}